// Round 1
// baseline (3362.555 us; speedup 1.0000x reference)
//
#include <hip/hip_runtime.h>

typedef __bf16 bf16x8 __attribute__((ext_vector_type(8)));
typedef float f32x4 __attribute__((ext_vector_type(4)));

__device__ __forceinline__ unsigned short f2bf(float f) {
  union { float f; unsigned u; } c; c.f = f;
  unsigned u = c.u;
  u = (u + 0x7fffu + ((u >> 16) & 1u)) >> 16;
  return (unsigned short)u;
}

// ---------- graph prep ----------
__global__ void k_count(const int* __restrict__ src_g, const int* __restrict__ dst_g,
                        const int* __restrict__ dst_s,
                        int* deg_og, int* deg_ig, int* cnt_s, int E)
{
  int e = blockIdx.x * blockDim.x + threadIdx.x;
  if (e >= E) return;
  atomicAdd(&deg_og[src_g[e]], 1);
  atomicAdd(&deg_ig[dst_g[e]], 1);
  atomicAdd(&cnt_s[dst_s[e]], 1);
}

__global__ void k_norms(const int* __restrict__ deg_og, const int* __restrict__ deg_ig,
                        float* __restrict__ ns, float* __restrict__ nd, int N)
{
  int i = blockIdx.x * blockDim.x + threadIdx.x;
  if (i >= N) return;
  int a = deg_og[i]; ns[i] = a > 0 ? rsqrtf((float)a) : 0.f;
  int b = deg_ig[i]; nd[i] = b > 0 ? rsqrtf((float)b) : 0.f;
}

__global__ __launch_bounds__(1024) void k_scan(const int* __restrict__ deg, int* __restrict__ offs, int N)
{
  __shared__ int lds[1024];
  __shared__ int carry_s;
  const int t = threadIdx.x;
  if (t == 0) { carry_s = 0; offs[0] = 0; }
  __syncthreads();
  for (int base = 0; base < N; base += 1024) {
    const int i = base + t;
    int v = (i < N) ? deg[i] : 0;
    lds[t] = v;
    __syncthreads();
    for (int o = 1; o < 1024; o <<= 1) {
      int tmp = (t >= o) ? lds[t - o] : 0;
      __syncthreads();
      lds[t] += tmp;
      __syncthreads();
    }
    const int carry = carry_s;
    if (i < N) offs[i + 1] = lds[t] + carry;
    __syncthreads();
    if (t == 1023) carry_s = carry + lds[1023];
    __syncthreads();
  }
}

__global__ void k_fill(const int* __restrict__ src_g, const int* __restrict__ dst_g,
                       const int* __restrict__ offs, int* cursor, int* __restrict__ csr_src, int E)
{
  int e = blockIdx.x * blockDim.x + threadIdx.x;
  if (e >= E) return;
  int d = dst_g[e];
  int p = atomicAdd(&cursor[d], 1);
  csr_src[offs[d] + p] = src_g[e];
}

// ---------- fp32 tiled GEMM: C[M,Nc] = A[M,K] @ W[K,Nc] (+bias, opt relu) ----------
__global__ __launch_bounds__(256) void k_gemm(const float* __restrict__ A, const float* __restrict__ W,
                                              const float* __restrict__ bias, float* __restrict__ C,
                                              int M, int K, int Nc, int relu)
{
  __shared__ float As[16][65];
  __shared__ float Bs[16][65];
  const int tid = threadIdx.x;
  const int tx = tid & 15, ty = tid >> 4;
  const int bm = blockIdx.x * 64, bn = blockIdx.y * 64;
  float acc[4][4] = {};
  for (int k0 = 0; k0 < K; k0 += 16) {
    #pragma unroll
    for (int i = 0; i < 4; ++i) {
      int idx = tid + 256 * i;
      int ml = idx >> 4, kk = idx & 15;
      int mg = bm + ml; mg = mg < M ? mg : M - 1;
      As[kk][ml] = A[(size_t)mg * K + k0 + kk];
    }
    #pragma unroll
    for (int i = 0; i < 4; ++i) {
      int idx = tid + 256 * i;
      int kk = idx >> 6, nl = idx & 63;
      Bs[kk][nl] = W[(size_t)(k0 + kk) * Nc + bn + nl];
    }
    __syncthreads();
    #pragma unroll
    for (int kk = 0; kk < 16; ++kk) {
      float a[4], b[4];
      #pragma unroll
      for (int i = 0; i < 4; ++i) a[i] = As[kk][ty + 16 * i];
      #pragma unroll
      for (int j = 0; j < 4; ++j) b[j] = Bs[kk][tx + 16 * j];
      #pragma unroll
      for (int i = 0; i < 4; ++i)
        #pragma unroll
        for (int j = 0; j < 4; ++j)
          acc[i][j] += a[i] * b[j];
    }
    __syncthreads();
  }
  #pragma unroll
  for (int i = 0; i < 4; ++i) {
    int r = bm + ty + 16 * i;
    if (r >= M) continue;
    #pragma unroll
    for (int j = 0; j < 4; ++j) {
      int c = bn + tx + 16 * j;
      float v = acc[i][j];
      if (bias) v += bias[c];
      if (relu) v = fmaxf(v, 0.f);
      C[(size_t)r * Nc + c] = v;
    }
  }
}

// ---------- GCN aggregate + epilogue (agg*nd + b, opt relu) ----------
__global__ __launch_bounds__(256) void k_aggregate(const float* __restrict__ h,
    const int* __restrict__ offs, const int* __restrict__ csr_src,
    const float* __restrict__ ns, const float* __restrict__ nd,
    const float* __restrict__ bias, float* __restrict__ out, int F, int relu)
{
  const int i = blockIdx.x;
  const int t = threadIdx.x;
  const int s0 = offs[i], s1 = offs[i + 1];
  float acc0 = 0.f, acc1 = 0.f;
  for (int k = s0; k < s1; ++k) {
    const int s = csr_src[k];
    const float w = ns[s];
    const float* hr = h + (size_t)s * F;
    acc0 += hr[t] * w;
    if (F == 512) acc1 += hr[t + 256] * w;
  }
  const float ndv = nd[i];
  float o0 = acc0 * ndv + bias[t];
  if (relu) o0 = fmaxf(o0, 0.f);
  out[(size_t)i * F + t] = o0;
  if (F == 512) {
    float o1 = acc1 * ndv + bias[t + 256];
    if (relu) o1 = fmaxf(o1, 0.f);
    out[(size_t)i * F + t + 256] = o1;
  }
}

// ---------- row normalize: optional fp32 out, optional bf16 out ----------
__global__ __launch_bounds__(256) void k_normrows(const float* __restrict__ X,
    float* __restrict__ outf, unsigned short* __restrict__ outb, int Nrows)
{
  const int wid = threadIdx.x >> 6, lane = threadIdx.x & 63;
  const int row = blockIdx.x * 4 + wid;
  if (row >= Nrows) return;
  const float4 v = ((const float4*)(X + (size_t)row * 256))[lane];
  float ss = v.x * v.x + v.y * v.y + v.z * v.z + v.w * v.w;
  #pragma unroll
  for (int m = 1; m < 64; m <<= 1) ss += __shfl_xor(ss, m);
  const float inv = 1.f / fmaxf(sqrtf(ss), 1e-12f);
  float4 o; o.x = v.x * inv; o.y = v.y * inv; o.z = v.z * inv; o.w = v.w * inv;
  if (outf) ((float4*)(outf + (size_t)row * 256))[lane] = o;
  if (outb) {
    ushort4 u;
    u.x = f2bf(o.x); u.y = f2bf(o.y); u.z = f2bf(o.z); u.w = f2bf(o.w);
    ((ushort4*)(outb + (size_t)row * 256))[lane] = u;
  }
}

// ---------- edge sim: sim[e] = <un[src], q[dst]>/tau ; pos_sum[dst] += sim ----------
__global__ __launch_bounds__(256) void k_edge_sim(const float* __restrict__ un,
    const float* __restrict__ q, const int* __restrict__ src, const int* __restrict__ dst,
    const float* __restrict__ tau_p, float* __restrict__ sim, float* __restrict__ pos_sum, int E)
{
  const int w = blockIdx.x * 4 + (threadIdx.x >> 6);
  if (w >= E) return;
  const int lane = threadIdx.x & 63;
  const int s = src[w], d = dst[w];
  const float4 a = ((const float4*)(un + (size_t)s * 256))[lane];
  const float4 b = ((const float4*)(q + (size_t)d * 256))[lane];
  float dot = a.x * b.x + a.y * b.y + a.z * b.z + a.w * b.w;
  #pragma unroll
  for (int m = 1; m < 64; m <<= 1) dot += __shfl_xor(dot, m);
  if (lane == 0) {
    const float sv = dot / tau_p[0];
    sim[w] = sv;
    atomicAdd(&pos_sum[d], sv);
  }
}

// ---------- neg_sim[i] = sum_j exp(z_i.z_j/tau) + sum_j exp(z_i.stu_j/tau), bf16 MFMA ----------
__global__ __launch_bounds__(256) void k_negsim(const unsigned short* __restrict__ zb,
                                                const unsigned short* __restrict__ sb,
                                                const float* __restrict__ tau_p,
                                                float* __restrict__ negsim, int N)
{
  __shared__ float4 lds4[64 * 33];   // 64 rows x 512B, pitch 528B (33 float4) to dodge bank conflicts
  const int tid = threadIdx.x;
  const int lane = tid & 63, wid = tid >> 6;
  const int ntiles = N >> 4;
  int itile = blockIdx.x * 4 + wid;
  const bool valid = itile < ntiles;
  if (!valid) itile = 0;
  const int i0 = itile << 4;
  const float inv_tau = 1.0f / tau_p[0];

  // A fragments: rows i0..i0+15 of zb, layout row=lane&15, k=(lane>>4)*8 + ks*32 + [0..7]
  bf16x8 afrag[8];
  {
    const unsigned short* arow = zb + (size_t)(i0 + (lane & 15)) * 256 + ((lane >> 4) << 3);
    #pragma unroll
    for (int ks = 0; ks < 8; ++ks)
      afrag[ks] = *(const bf16x8*)(arow + ks * 32);
  }

  float psum[4] = {0.f, 0.f, 0.f, 0.f};
  const int total = 2 * N;
  for (int j0 = 0; j0 < total; j0 += 64) {
    const int rows = min(64, total - j0);
    __syncthreads();
    for (int idx = tid; idx < (rows << 5); idx += 256) {
      const int r = idx >> 5, c = idx & 31;
      const int g = j0 + r;
      const unsigned short* srcp = (g < N) ? (zb + (size_t)g * 256)
                                           : (sb + (size_t)(g - N) * 256);
      lds4[r * 33 + c] = ((const float4*)srcp)[c];
    }
    __syncthreads();
    const int nsub = rows >> 4;
    for (int sub = 0; sub < nsub; ++sub) {
      const float4* bbase = &lds4[(sub * 16 + (lane & 15)) * 33 + (lane >> 4)];
      f32x4 acc = {0.f, 0.f, 0.f, 0.f};
      #pragma unroll
      for (int ks = 0; ks < 8; ++ks) {
        bf16x8 bfrag = *(const bf16x8*)(bbase + ks * 4);
        acc = __builtin_amdgcn_mfma_f32_16x16x32_bf16(afrag[ks], bfrag, acc, 0, 0, 0);
      }
      #pragma unroll
      for (int j = 0; j < 4; ++j)
        psum[j] += __expf(acc[j] * inv_tau);
    }
  }
  // C/D layout: col=lane&15, row=(lane>>4)*4+j -> reduce over cols = lanes within 16-group
  #pragma unroll
  for (int j = 0; j < 4; ++j) {
    float v = psum[j];
    v += __shfl_xor(v, 1);
    v += __shfl_xor(v, 2);
    v += __shfl_xor(v, 4);
    v += __shfl_xor(v, 8);
    if (valid && (lane & 15) == 0)
      negsim[i0 + ((lane >> 4) << 2) + j] = v;
  }
}

// ---------- edge neg: m = log(neg_sim[dst] + exp(sim)); neg_sum[dst] += m ----------
__global__ void k_edge_neg(const float* __restrict__ negsim, const float* __restrict__ sim,
                           const int* __restrict__ dst, float* __restrict__ neg_sum, int E)
{
  const int e = blockIdx.x * blockDim.x + threadIdx.x;
  if (e >= E) return;
  const int d = dst[e];
  const float m = logf(negsim[d] + __expf(sim[e]));
  atomicAdd(&neg_sum[d], m);
}

// ---------- loss = mean_i (-pos_sum + neg_sum)/max(cnt,1) ----------
__global__ __launch_bounds__(1024) void k_loss(const float* __restrict__ pos, const float* __restrict__ neg,
                                               const int* __restrict__ cnt, int N,
                                               float* __restrict__ out, int add)
{
  __shared__ float lds[1024];
  float s = 0.f;
  for (int i = threadIdx.x; i < N; i += 1024) {
    float denom = fmaxf((float)cnt[i], 1.f);
    s += (-pos[i] + neg[i]) / denom;
  }
  lds[threadIdx.x] = s;
  __syncthreads();
  for (int o = 512; o > 0; o >>= 1) {
    if (threadIdx.x < o) lds[threadIdx.x] += lds[threadIdx.x + o];
    __syncthreads();
  }
  if (threadIdx.x == 0) {
    float v = lds[0] / (float)N;
    if (add) out[0] += v; else out[0] = v;
  }
}

extern "C" void kernel_launch(void* const* d_in, const int* in_sizes, int n_in,
                              void* d_out, int out_size, void* d_ws, size_t ws_size,
                              hipStream_t stream)
{
  const float* feat  = (const float*)d_in[0];
  const int* src_g   = (const int*)d_in[1];
  const int* dst_g   = (const int*)d_in[2];
  const int* src_s   = (const int*)d_in[3];
  const int* dst_s   = (const int*)d_in[4];
  const float* tau1  = (const float*)d_in[5];
  const float* tau2  = (const float*)d_in[6];
  const float* W1a   = (const float*)d_in[7];
  const float* b1a   = (const float*)d_in[8];
  const float* W1b   = (const float*)d_in[9];
  const float* b1b   = (const float*)d_in[10];
  const float* W1a_t = (const float*)d_in[11];
  const float* b1a_t = (const float*)d_in[12];
  const float* W1b_t = (const float*)d_in[13];
  const float* b1b_t = (const float*)d_in[14];
  const float* W2    = (const float*)d_in[15];
  const float* b2    = (const float*)d_in[16];
  const float* W2_t  = (const float*)d_in[17];
  const float* b2_t  = (const float*)d_in[18];
  const float* Wp    = (const float*)d_in[19];
  const float* bp    = (const float*)d_in[20];

  const int N = in_sizes[0] / 512;
  const int E = in_sizes[1];

  float* out  = (float*)d_out;
  float* v1   = out;
  float* u1   = out + (size_t)N * 256;
  float* v2   = out + (size_t)2 * N * 256;
  float* u2   = out + (size_t)3 * N * 256;
  float* loss = out + (size_t)4 * N * 256;

  char* ws = (char*)d_ws;
  size_t off = 0;
  auto alloc = [&](size_t bytes) -> char* {
    char* p = ws + off;
    off += (bytes + 255) & ~(size_t)255;
    return p;
  };
  int* zbase   = (int*)alloc((size_t)8 * N * 4);   // zeroed region
  int* deg_og  = zbase;
  int* deg_ig  = zbase + N;
  int* cnt_s   = zbase + 2 * N;
  int* cursor  = zbase + 3 * N;
  float* pos1  = (float*)(zbase + 4 * N);
  float* neg1  = (float*)(zbase + 5 * N);
  float* pos2  = (float*)(zbase + 6 * N);
  float* neg2  = (float*)(zbase + 7 * N);
  int* offs    = (int*)alloc((size_t)(N + 1) * 4);
  int* csr_src = (int*)alloc((size_t)E * 4);
  float* ns    = (float*)alloc((size_t)N * 4);
  float* nd    = (float*)alloc((size_t)N * 4);
  float* negs  = (float*)alloc((size_t)N * 4);
  float* B1 = (float*)alloc((size_t)N * 512 * 4);
  float* B2 = (float*)alloc((size_t)N * 512 * 4);
  float* B3 = (float*)alloc((size_t)N * 512 * 4);
  float* B4 = (float*)alloc((size_t)N * 512 * 4);
  if (off > ws_size) return;  // workspace too small -> visible failure

  float* h1  = B1; float* h1t = B2; float* a1 = B3; float* a1t = B4;
  float* h2  = B1; float* h2t = B2;                       // reuse after layer-1 agg
  float* q   = B3;                                        // N*256 f32 (a1 dead)
  float* un  = B3 + (size_t)N * 256;
  unsigned short* zb = (unsigned short*)B4;               // N*256 bf16 (a1t dead)
  unsigned short* sb = zb + (size_t)N * 256;
  float* sim = (float*)((char*)B4 + (size_t)N * 1024);    // after zb+sb

  const int mt = (N + 63) / 64;
  const int eb = (E + 255) / 256;
  const int negb = ((N / 16) + 3) / 4;

  hipMemsetAsync(zbase, 0, (size_t)8 * N * 4, stream);
  k_count<<<eb, 256, 0, stream>>>(src_g, dst_g, dst_s, deg_og, deg_ig, cnt_s, E);
  k_norms<<<(N + 255) / 256, 256, 0, stream>>>(deg_og, deg_ig, ns, nd, N);
  k_scan<<<1, 1024, 0, stream>>>(deg_ig, offs, N);
  k_fill<<<eb, 256, 0, stream>>>(src_g, dst_g, offs, cursor, csr_src, E);

  // GCN encoder (online + target)
  k_gemm<<<dim3(mt, 8), 256, 0, stream>>>(feat, W1a,   nullptr, h1,  N, 512, 512, 0);
  k_gemm<<<dim3(mt, 8), 256, 0, stream>>>(feat, W1a_t, nullptr, h1t, N, 512, 512, 0);
  k_aggregate<<<N, 256, 0, stream>>>(h1,  offs, csr_src, ns, nd, b1a,   a1,  512, 1);
  k_aggregate<<<N, 256, 0, stream>>>(h1t, offs, csr_src, ns, nd, b1a_t, a1t, 512, 1);
  k_gemm<<<dim3(mt, 4), 256, 0, stream>>>(a1,  W1b,   nullptr, h2,  N, 512, 256, 0);
  k_gemm<<<dim3(mt, 4), 256, 0, stream>>>(a1t, W1b_t, nullptr, h2t, N, 512, 256, 0);
  k_aggregate<<<N, 256, 0, stream>>>(h2,  offs, csr_src, ns, nd, b1b,   v1, 256, 0);
  k_aggregate<<<N, 256, 0, stream>>>(h2t, offs, csr_src, ns, nd, b1b_t, u1, 256, 0);
  // linear encoder
  k_gemm<<<dim3(mt, 4), 256, 0, stream>>>(feat, W2,   b2,   v2, N, 512, 256, 0);
  k_gemm<<<dim3(mt, 4), 256, 0, stream>>>(feat, W2_t, b2_t, u2, N, 512, 256, 0);

  // ---- scores branch 1 ----
  k_gemm<<<dim3(mt, 4), 256, 0, stream>>>(v1, Wp, bp, q, N, 256, 256, 0);
  k_normrows<<<(N + 3) / 4, 256, 0, stream>>>(q,  q,       nullptr, N);
  k_normrows<<<(N + 3) / 4, 256, 0, stream>>>(u1, un,      sb,      N);
  k_normrows<<<(N + 3) / 4, 256, 0, stream>>>(v1, nullptr, zb,      N);
  k_edge_sim<<<(E + 3) / 4, 256, 0, stream>>>(un, q, src_s, dst_s, tau1, sim, pos1, E);
  k_negsim<<<negb, 256, 0, stream>>>(zb, sb, tau1, negs, N);
  k_edge_neg<<<eb, 256, 0, stream>>>(negs, sim, dst_s, neg1, E);
  k_loss<<<1, 1024, 0, stream>>>(pos1, neg1, cnt_s, N, loss, 0);

  // ---- scores branch 2 ----
  k_gemm<<<dim3(mt, 4), 256, 0, stream>>>(v2, Wp, bp, q, N, 256, 256, 0);
  k_normrows<<<(N + 3) / 4, 256, 0, stream>>>(q,  q,       nullptr, N);
  k_normrows<<<(N + 3) / 4, 256, 0, stream>>>(u2, un,      sb,      N);
  k_normrows<<<(N + 3) / 4, 256, 0, stream>>>(v2, nullptr, zb,      N);
  k_edge_sim<<<(E + 3) / 4, 256, 0, stream>>>(un, q, src_s, dst_s, tau2, sim, pos2, E);
  k_negsim<<<negb, 256, 0, stream>>>(zb, sb, tau2, negs, N);
  k_edge_neg<<<eb, 256, 0, stream>>>(negs, sim, dst_s, neg2, E);
  k_loss<<<1, 1024, 0, stream>>>(pos2, neg2, cnt_s, N, loss, 1);
}

// Round 2
// 1565.010 us; speedup vs baseline: 2.1486x; 2.1486x over previous
//
#include <hip/hip_runtime.h>

typedef __bf16 bf16x8 __attribute__((ext_vector_type(8)));
typedef float f32x4 __attribute__((ext_vector_type(4)));

__device__ __forceinline__ unsigned short f2bf(float f) {
  union { float f; unsigned u; } c; c.f = f;
  unsigned u = c.u;
  u = (u + 0x7fffu + ((u >> 16) & 1u)) >> 16;
  return (unsigned short)u;
}

// ---------- graph prep ----------
__global__ void k_count(const int* __restrict__ src_g, const int* __restrict__ dst_g,
                        const int* __restrict__ dst_s,
                        int* deg_og, int* deg_ig, int* cnt_s, int E)
{
  int e = blockIdx.x * blockDim.x + threadIdx.x;
  if (e >= E) return;
  atomicAdd(&deg_og[src_g[e]], 1);
  atomicAdd(&deg_ig[dst_g[e]], 1);
  atomicAdd(&cnt_s[dst_s[e]], 1);
}

__global__ void k_norms(const int* __restrict__ deg_og, const int* __restrict__ deg_ig,
                        float* __restrict__ ns, float* __restrict__ nd, int N)
{
  int i = blockIdx.x * blockDim.x + threadIdx.x;
  if (i >= N) return;
  int a = deg_og[i]; ns[i] = a > 0 ? rsqrtf((float)a) : 0.f;
  int b = deg_ig[i]; nd[i] = b > 0 ? rsqrtf((float)b) : 0.f;
}

__global__ __launch_bounds__(1024) void k_scan(const int* __restrict__ deg, int* __restrict__ offs, int N)
{
  __shared__ int lds[1024];
  __shared__ int carry_s;
  const int t = threadIdx.x;
  if (t == 0) { carry_s = 0; offs[0] = 0; }
  __syncthreads();
  for (int base = 0; base < N; base += 1024) {
    const int i = base + t;
    int v = (i < N) ? deg[i] : 0;
    lds[t] = v;
    __syncthreads();
    for (int o = 1; o < 1024; o <<= 1) {
      int tmp = (t >= o) ? lds[t - o] : 0;
      __syncthreads();
      lds[t] += tmp;
      __syncthreads();
    }
    const int carry = carry_s;
    if (i < N) offs[i + 1] = lds[t] + carry;
    __syncthreads();
    if (t == 1023) carry_s = carry + lds[1023];
    __syncthreads();
  }
}

__global__ void k_fill(const int* __restrict__ src_g, const int* __restrict__ dst_g,
                       const int* __restrict__ offs, int* cursor, int* __restrict__ csr_src, int E)
{
  int e = blockIdx.x * blockDim.x + threadIdx.x;
  if (e >= E) return;
  int d = dst_g[e];
  int p = atomicAdd(&cursor[d], 1);
  csr_src[offs[d] + p] = src_g[e];
}

// ---------- fp32 tiled GEMM: C[M,Nc] = A[M,K] @ W[K,Nc] (+bias, opt relu) ----------
__global__ __launch_bounds__(256) void k_gemm(const float* __restrict__ A, const float* __restrict__ W,
                                              const float* __restrict__ bias, float* __restrict__ C,
                                              int M, int K, int Nc, int relu)
{
  __shared__ float As[16][65];
  __shared__ float Bs[16][65];
  const int tid = threadIdx.x;
  const int tx = tid & 15, ty = tid >> 4;
  const int bm = blockIdx.x * 64, bn = blockIdx.y * 64;
  float acc[4][4] = {};
  for (int k0 = 0; k0 < K; k0 += 16) {
    #pragma unroll
    for (int i = 0; i < 4; ++i) {
      int idx = tid + 256 * i;
      int ml = idx >> 4, kk = idx & 15;
      int mg = bm + ml; mg = mg < M ? mg : M - 1;
      As[kk][ml] = A[(size_t)mg * K + k0 + kk];
    }
    #pragma unroll
    for (int i = 0; i < 4; ++i) {
      int idx = tid + 256 * i;
      int kk = idx >> 6, nl = idx & 63;
      Bs[kk][nl] = W[(size_t)(k0 + kk) * Nc + bn + nl];
    }
    __syncthreads();
    #pragma unroll
    for (int kk = 0; kk < 16; ++kk) {
      float a[4], b[4];
      #pragma unroll
      for (int i = 0; i < 4; ++i) a[i] = As[kk][ty + 16 * i];
      #pragma unroll
      for (int j = 0; j < 4; ++j) b[j] = Bs[kk][tx + 16 * j];
      #pragma unroll
      for (int i = 0; i < 4; ++i)
        #pragma unroll
        for (int j = 0; j < 4; ++j)
          acc[i][j] += a[i] * b[j];
    }
    __syncthreads();
  }
  #pragma unroll
  for (int i = 0; i < 4; ++i) {
    int r = bm + ty + 16 * i;
    if (r >= M) continue;
    #pragma unroll
    for (int j = 0; j < 4; ++j) {
      int c = bn + tx + 16 * j;
      float v = acc[i][j];
      if (bias) v += bias[c];
      if (relu) v = fmaxf(v, 0.f);
      C[(size_t)r * Nc + c] = v;
    }
  }
}

// ---------- GCN aggregate + epilogue (agg*nd + b, opt relu) ----------
__global__ __launch_bounds__(256) void k_aggregate(const float* __restrict__ h,
    const int* __restrict__ offs, const int* __restrict__ csr_src,
    const float* __restrict__ ns, const float* __restrict__ nd,
    const float* __restrict__ bias, float* __restrict__ out, int F, int relu)
{
  const int i = blockIdx.x;
  const int t = threadIdx.x;
  const int s0 = offs[i], s1 = offs[i + 1];
  float acc0 = 0.f, acc1 = 0.f;
  for (int k = s0; k < s1; ++k) {
    const int s = csr_src[k];
    const float w = ns[s];
    const float* hr = h + (size_t)s * F;
    acc0 += hr[t] * w;
    if (F == 512) acc1 += hr[t + 256] * w;
  }
  const float ndv = nd[i];
  float o0 = acc0 * ndv + bias[t];
  if (relu) o0 = fmaxf(o0, 0.f);
  out[(size_t)i * F + t] = o0;
  if (F == 512) {
    float o1 = acc1 * ndv + bias[t + 256];
    if (relu) o1 = fmaxf(o1, 0.f);
    out[(size_t)i * F + t + 256] = o1;
  }
}

// ---------- row normalize: optional fp32 out, optional bf16 out ----------
__global__ __launch_bounds__(256) void k_normrows(const float* __restrict__ X,
    float* __restrict__ outf, unsigned short* __restrict__ outb, int Nrows)
{
  const int wid = threadIdx.x >> 6, lane = threadIdx.x & 63;
  const int row = blockIdx.x * 4 + wid;
  if (row >= Nrows) return;
  const float4 v = ((const float4*)(X + (size_t)row * 256))[lane];
  float ss = v.x * v.x + v.y * v.y + v.z * v.z + v.w * v.w;
  #pragma unroll
  for (int m = 1; m < 64; m <<= 1) ss += __shfl_xor(ss, m);
  const float inv = 1.f / fmaxf(sqrtf(ss), 1e-12f);
  float4 o; o.x = v.x * inv; o.y = v.y * inv; o.z = v.z * inv; o.w = v.w * inv;
  if (outf) ((float4*)(outf + (size_t)row * 256))[lane] = o;
  if (outb) {
    ushort4 u;
    u.x = f2bf(o.x); u.y = f2bf(o.y); u.z = f2bf(o.z); u.w = f2bf(o.w);
    ((ushort4*)(outb + (size_t)row * 256))[lane] = u;
  }
}

// ---------- edge sim: sim[e] = <un[src], q[dst]>/tau ; pos_sum[dst] += sim ----------
__global__ __launch_bounds__(256) void k_edge_sim(const float* __restrict__ un,
    const float* __restrict__ q, const int* __restrict__ src, const int* __restrict__ dst,
    const float* __restrict__ tau_p, float* __restrict__ sim, float* __restrict__ pos_sum, int E)
{
  const int w = blockIdx.x * 4 + (threadIdx.x >> 6);
  if (w >= E) return;
  const int lane = threadIdx.x & 63;
  const int s = src[w], d = dst[w];
  const float4 a = ((const float4*)(un + (size_t)s * 256))[lane];
  const float4 b = ((const float4*)(q + (size_t)d * 256))[lane];
  float dot = a.x * b.x + a.y * b.y + a.z * b.z + a.w * b.w;
  #pragma unroll
  for (int m = 1; m < 64; m <<= 1) dot += __shfl_xor(dot, m);
  if (lane == 0) {
    const float sv = dot / tau_p[0];
    sim[w] = sv;
    atomicAdd(&pos_sum[d], sv);
  }
}

// ---------- neg_sim accumulate (j-split): negsim[i] += sum_{j in chunk} exp(z_i.cat_j/tau) ----------
// Each wave owns TWO i-tiles (32 rows) in registers; 4 waves/block share the LDS j-tile.
// Grid: x = pair-groups (4 pairs/block), y = j-chunks. Partials atomically added to negsim.
#define NEG_JSPLIT 16
__global__ __launch_bounds__(256) void k_negsim(const unsigned short* __restrict__ zb,
                                                const unsigned short* __restrict__ sb,
                                                const float* __restrict__ tau_p,
                                                float* __restrict__ negsim, int N)
{
  __shared__ float4 lds4[64 * 33];   // 64 rows x 512B, pitch 528B -> 2-way (free) on ds_read_b128
  const int tid = threadIdx.x;
  const int lane = tid & 63, wid = tid >> 6;
  const int ntiles = N >> 4;
  const int pair = blockIdx.x * 4 + wid;
  int it0 = pair * 2, it1 = pair * 2 + 1;
  const bool v0 = it0 < ntiles, v1 = it1 < ntiles;
  if (!v0) it0 = 0;
  if (!v1) it1 = it0;            // clamp: compute garbage, never written
  const int i00 = it0 << 4, i01 = it1 << 4;
  const float k_exp = 1.0f / tau_p[0];

  // A fragments for both i-tiles: row=lane&15, k=(lane>>4)*8 + ks*32 + [0..7]
  bf16x8 a0[8], a1[8];
  {
    const unsigned short* r0 = zb + (size_t)(i00 + (lane & 15)) * 256 + ((lane >> 4) << 3);
    const unsigned short* r1 = zb + (size_t)(i01 + (lane & 15)) * 256 + ((lane >> 4) << 3);
    #pragma unroll
    for (int ks = 0; ks < 8; ++ks) {
      a0[ks] = *(const bf16x8*)(r0 + ks * 32);
      a1[ks] = *(const bf16x8*)(r1 + ks * 32);
    }
  }

  const int total = 2 * N;
  const int chunk = ((total + NEG_JSPLIT * 64 - 1) / (NEG_JSPLIT * 64)) * 64;
  const int jbeg = blockIdx.y * chunk;
  const int jend = min(total, jbeg + chunk);

  float ps0[4] = {0.f, 0.f, 0.f, 0.f};
  float ps1[4] = {0.f, 0.f, 0.f, 0.f};
  for (int j0 = jbeg; j0 < jend; j0 += 64) {
    const int rows = min(64, jend - j0);        // always a multiple of 16
    __syncthreads();
    for (int idx = tid; idx < (rows << 5); idx += 256) {
      const int r = idx >> 5, c = idx & 31;
      const int g = j0 + r;
      const unsigned short* srcp = (g < N) ? (zb + (size_t)g * 256)
                                           : (sb + (size_t)(g - N) * 256);
      lds4[r * 33 + c] = ((const float4*)srcp)[c];
    }
    __syncthreads();
    if (rows == 64) {
      f32x4 acc0[4] = {}, acc1[4] = {};
      #pragma unroll
      for (int ks = 0; ks < 8; ++ks) {
        #pragma unroll
        for (int sub = 0; sub < 4; ++sub) {
          const float4* bb = &lds4[(sub * 16 + (lane & 15)) * 33 + (lane >> 4)];
          bf16x8 bfrag = *(const bf16x8*)(bb + ks * 4);
          acc0[sub] = __builtin_amdgcn_mfma_f32_16x16x32_bf16(a0[ks], bfrag, acc0[sub], 0, 0, 0);
          acc1[sub] = __builtin_amdgcn_mfma_f32_16x16x32_bf16(a1[ks], bfrag, acc1[sub], 0, 0, 0);
        }
      }
      #pragma unroll
      for (int sub = 0; sub < 4; ++sub)
        #pragma unroll
        for (int j = 0; j < 4; ++j) {
          ps0[j] += __expf(acc0[sub][j] * k_exp);
          ps1[j] += __expf(acc1[sub][j] * k_exp);
        }
    } else {
      const int nsub = rows >> 4;
      for (int sub = 0; sub < nsub; ++sub) {
        const float4* bb = &lds4[(sub * 16 + (lane & 15)) * 33 + (lane >> 4)];
        f32x4 acc0 = {}, acc1 = {};
        #pragma unroll
        for (int ks = 0; ks < 8; ++ks) {
          bf16x8 bfrag = *(const bf16x8*)(bb + ks * 4);
          acc0 = __builtin_amdgcn_mfma_f32_16x16x32_bf16(a0[ks], bfrag, acc0, 0, 0, 0);
          acc1 = __builtin_amdgcn_mfma_f32_16x16x32_bf16(a1[ks], bfrag, acc1, 0, 0, 0);
        }
        #pragma unroll
        for (int j = 0; j < 4; ++j) {
          ps0[j] += __expf(acc0[j] * k_exp);
          ps1[j] += __expf(acc1[j] * k_exp);
        }
      }
    }
  }
  // C/D layout: col=lane&15, row=(lane>>4)*4+j -> reduce over 16 cols within each group
  #pragma unroll
  for (int j = 0; j < 4; ++j) {
    float x0 = ps0[j], x1 = ps1[j];
    x0 += __shfl_xor(x0, 1); x1 += __shfl_xor(x1, 1);
    x0 += __shfl_xor(x0, 2); x1 += __shfl_xor(x1, 2);
    x0 += __shfl_xor(x0, 4); x1 += __shfl_xor(x1, 4);
    x0 += __shfl_xor(x0, 8); x1 += __shfl_xor(x1, 8);
    if ((lane & 15) == 0) {
      const int r = ((lane >> 4) << 2) + j;
      if (v0) atomicAdd(&negsim[i00 + r], x0);
      if (v1) atomicAdd(&negsim[i01 + r], x1);
    }
  }
}

// ---------- edge neg: m = log(neg_sim[dst] + exp(sim)); neg_sum[dst] += m ----------
__global__ void k_edge_neg(const float* __restrict__ negsim, const float* __restrict__ sim,
                           const int* __restrict__ dst, float* __restrict__ neg_sum, int E)
{
  const int e = blockIdx.x * blockDim.x + threadIdx.x;
  if (e >= E) return;
  const int d = dst[e];
  const float m = logf(negsim[d] + __expf(sim[e]));
  atomicAdd(&neg_sum[d], m);
}

// ---------- loss = mean_i (-pos_sum + neg_sum)/max(cnt,1) ----------
__global__ __launch_bounds__(1024) void k_loss(const float* __restrict__ pos, const float* __restrict__ neg,
                                               const int* __restrict__ cnt, int N,
                                               float* __restrict__ out, int add)
{
  __shared__ float lds[1024];
  float s = 0.f;
  for (int i = threadIdx.x; i < N; i += 1024) {
    float denom = fmaxf((float)cnt[i], 1.f);
    s += (-pos[i] + neg[i]) / denom;
  }
  lds[threadIdx.x] = s;
  __syncthreads();
  for (int o = 512; o > 0; o >>= 1) {
    if (threadIdx.x < o) lds[threadIdx.x] += lds[threadIdx.x + o];
    __syncthreads();
  }
  if (threadIdx.x == 0) {
    float v = lds[0] / (float)N;
    if (add) out[0] += v; else out[0] = v;
  }
}

extern "C" void kernel_launch(void* const* d_in, const int* in_sizes, int n_in,
                              void* d_out, int out_size, void* d_ws, size_t ws_size,
                              hipStream_t stream)
{
  const float* feat  = (const float*)d_in[0];
  const int* src_g   = (const int*)d_in[1];
  const int* dst_g   = (const int*)d_in[2];
  const int* src_s   = (const int*)d_in[3];
  const int* dst_s   = (const int*)d_in[4];
  const float* tau1  = (const float*)d_in[5];
  const float* tau2  = (const float*)d_in[6];
  const float* W1a   = (const float*)d_in[7];
  const float* b1a   = (const float*)d_in[8];
  const float* W1b   = (const float*)d_in[9];
  const float* b1b   = (const float*)d_in[10];
  const float* W1a_t = (const float*)d_in[11];
  const float* b1a_t = (const float*)d_in[12];
  const float* W1b_t = (const float*)d_in[13];
  const float* b1b_t = (const float*)d_in[14];
  const float* W2    = (const float*)d_in[15];
  const float* b2    = (const float*)d_in[16];
  const float* W2_t  = (const float*)d_in[17];
  const float* b2_t  = (const float*)d_in[18];
  const float* Wp    = (const float*)d_in[19];
  const float* bp    = (const float*)d_in[20];

  const int N = in_sizes[0] / 512;
  const int E = in_sizes[1];

  float* out  = (float*)d_out;
  float* v1   = out;
  float* u1   = out + (size_t)N * 256;
  float* v2   = out + (size_t)2 * N * 256;
  float* u2   = out + (size_t)3 * N * 256;
  float* loss = out + (size_t)4 * N * 256;

  char* ws = (char*)d_ws;
  size_t off = 0;
  auto alloc = [&](size_t bytes) -> char* {
    char* p = ws + off;
    off += (bytes + 255) & ~(size_t)255;
    return p;
  };
  int* zbase   = (int*)alloc((size_t)10 * N * 4);   // zeroed region
  int* deg_og  = zbase;
  int* deg_ig  = zbase + N;
  int* cnt_s   = zbase + 2 * N;
  int* cursor  = zbase + 3 * N;
  float* pos1  = (float*)(zbase + 4 * N);
  float* neg1  = (float*)(zbase + 5 * N);
  float* pos2  = (float*)(zbase + 6 * N);
  float* neg2  = (float*)(zbase + 7 * N);
  float* negs1 = (float*)(zbase + 8 * N);
  float* negs2 = (float*)(zbase + 9 * N);
  int* offs    = (int*)alloc((size_t)(N + 1) * 4);
  int* csr_src = (int*)alloc((size_t)E * 4);
  float* ns    = (float*)alloc((size_t)N * 4);
  float* nd    = (float*)alloc((size_t)N * 4);
  float* B1 = (float*)alloc((size_t)N * 512 * 4);
  float* B2 = (float*)alloc((size_t)N * 512 * 4);
  float* B3 = (float*)alloc((size_t)N * 512 * 4);
  float* B4 = (float*)alloc((size_t)N * 512 * 4);
  if (off > ws_size) return;  // workspace too small -> visible failure

  float* h1  = B1; float* h1t = B2; float* a1 = B3; float* a1t = B4;
  float* h2  = B1; float* h2t = B2;                       // reuse after layer-1 agg
  float* q   = B3;                                        // N*256 f32 (a1 dead)
  float* un  = B3 + (size_t)N * 256;
  unsigned short* zb = (unsigned short*)B4;               // N*256 bf16 (a1t dead)
  unsigned short* sb = zb + (size_t)N * 256;
  float* sim = (float*)((char*)B4 + (size_t)N * 1024);    // after zb+sb

  const int mt = (N + 63) / 64;
  const int eb = (E + 255) / 256;
  const int ntiles = N / 16;
  const int npairs = (ntiles + 1) / 2;
  const dim3 neggrid((npairs + 3) / 4, NEG_JSPLIT);

  hipMemsetAsync(zbase, 0, (size_t)10 * N * 4, stream);
  k_count<<<eb, 256, 0, stream>>>(src_g, dst_g, dst_s, deg_og, deg_ig, cnt_s, E);
  k_norms<<<(N + 255) / 256, 256, 0, stream>>>(deg_og, deg_ig, ns, nd, N);
  k_scan<<<1, 1024, 0, stream>>>(deg_ig, offs, N);
  k_fill<<<eb, 256, 0, stream>>>(src_g, dst_g, offs, cursor, csr_src, E);

  // GCN encoder (online + target)
  k_gemm<<<dim3(mt, 8), 256, 0, stream>>>(feat, W1a,   nullptr, h1,  N, 512, 512, 0);
  k_gemm<<<dim3(mt, 8), 256, 0, stream>>>(feat, W1a_t, nullptr, h1t, N, 512, 512, 0);
  k_aggregate<<<N, 256, 0, stream>>>(h1,  offs, csr_src, ns, nd, b1a,   a1,  512, 1);
  k_aggregate<<<N, 256, 0, stream>>>(h1t, offs, csr_src, ns, nd, b1a_t, a1t, 512, 1);
  k_gemm<<<dim3(mt, 4), 256, 0, stream>>>(a1,  W1b,   nullptr, h2,  N, 512, 256, 0);
  k_gemm<<<dim3(mt, 4), 256, 0, stream>>>(a1t, W1b_t, nullptr, h2t, N, 512, 256, 0);
  k_aggregate<<<N, 256, 0, stream>>>(h2,  offs, csr_src, ns, nd, b1b,   v1, 256, 0);
  k_aggregate<<<N, 256, 0, stream>>>(h2t, offs, csr_src, ns, nd, b1b_t, u1, 256, 0);
  // linear encoder
  k_gemm<<<dim3(mt, 4), 256, 0, stream>>>(feat, W2,   b2,   v2, N, 512, 256, 0);
  k_gemm<<<dim3(mt, 4), 256, 0, stream>>>(feat, W2_t, b2_t, u2, N, 512, 256, 0);

  // ---- scores branch 1 ----
  k_gemm<<<dim3(mt, 4), 256, 0, stream>>>(v1, Wp, bp, q, N, 256, 256, 0);
  k_normrows<<<(N + 3) / 4, 256, 0, stream>>>(q,  q,       nullptr, N);
  k_normrows<<<(N + 3) / 4, 256, 0, stream>>>(u1, un,      sb,      N);
  k_normrows<<<(N + 3) / 4, 256, 0, stream>>>(v1, nullptr, zb,      N);
  k_edge_sim<<<(E + 3) / 4, 256, 0, stream>>>(un, q, src_s, dst_s, tau1, sim, pos1, E);
  k_negsim<<<neggrid, 256, 0, stream>>>(zb, sb, tau1, negs1, N);
  k_edge_neg<<<eb, 256, 0, stream>>>(negs1, sim, dst_s, neg1, E);
  k_loss<<<1, 1024, 0, stream>>>(pos1, neg1, cnt_s, N, loss, 0);

  // ---- scores branch 2 ----
  k_gemm<<<dim3(mt, 4), 256, 0, stream>>>(v2, Wp, bp, q, N, 256, 256, 0);
  k_normrows<<<(N + 3) / 4, 256, 0, stream>>>(q,  q,       nullptr, N);
  k_normrows<<<(N + 3) / 4, 256, 0, stream>>>(u2, un,      sb,      N);
  k_normrows<<<(N + 3) / 4, 256, 0, stream>>>(v2, nullptr, zb,      N);
  k_edge_sim<<<(E + 3) / 4, 256, 0, stream>>>(un, q, src_s, dst_s, tau2, sim, pos2, E);
  k_negsim<<<neggrid, 256, 0, stream>>>(zb, sb, tau2, negs2, N);
  k_edge_neg<<<eb, 256, 0, stream>>>(negs2, sim, dst_s, neg2, E);
  k_loss<<<1, 1024, 0, stream>>>(pos2, neg2, cnt_s, N, loss, 1);
}

// Round 3
// 1208.928 us; speedup vs baseline: 2.7814x; 1.2945x over previous
//
#include <hip/hip_runtime.h>

typedef __bf16 bf16x8 __attribute__((ext_vector_type(8)));
typedef float f32x4 __attribute__((ext_vector_type(4)));

#define GLOAD16(gp, lp) __builtin_amdgcn_global_load_lds( \
    (const __attribute__((address_space(1))) void*)(gp), \
    (__attribute__((address_space(3))) void*)(lp), 16, 0, 0)

__device__ __forceinline__ unsigned short f2bf(float f) {
  union { float f; unsigned u; } c; c.f = f;
  unsigned u = c.u;
  u = (u + 0x7fffu + ((u >> 16) & 1u)) >> 16;
  return (unsigned short)u;
}
__device__ __forceinline__ float b2f(unsigned short u) {
  union { unsigned u; float f; } c; c.u = ((unsigned)u) << 16; return c.f;
}

// ---------- graph prep ----------
__global__ void k_count(const int* __restrict__ src_g, const int* __restrict__ dst_g,
                        const int* __restrict__ dst_s,
                        int* deg_og, int* deg_ig, int* cnt_s, int E)
{
  int e = blockIdx.x * blockDim.x + threadIdx.x;
  if (e >= E) return;
  atomicAdd(&deg_og[src_g[e]], 1);
  atomicAdd(&deg_ig[dst_g[e]], 1);
  atomicAdd(&cnt_s[dst_s[e]], 1);
}

__global__ void k_norms(const int* __restrict__ deg_og, const int* __restrict__ deg_ig,
                        float* __restrict__ ns, float* __restrict__ nd, int N)
{
  int i = blockIdx.x * blockDim.x + threadIdx.x;
  if (i >= N) return;
  int a = deg_og[i]; ns[i] = a > 0 ? rsqrtf((float)a) : 0.f;
  int b = deg_ig[i]; nd[i] = b > 0 ? rsqrtf((float)b) : 0.f;
}

__global__ __launch_bounds__(1024) void k_scan(const int* __restrict__ deg, int* __restrict__ offs, int N)
{
  __shared__ int lds[1024];
  __shared__ int carry_s;
  const int t = threadIdx.x;
  if (t == 0) { carry_s = 0; offs[0] = 0; }
  __syncthreads();
  for (int base = 0; base < N; base += 1024) {
    const int i = base + t;
    int v = (i < N) ? deg[i] : 0;
    lds[t] = v;
    __syncthreads();
    for (int o = 1; o < 1024; o <<= 1) {
      int tmp = (t >= o) ? lds[t - o] : 0;
      __syncthreads();
      lds[t] += tmp;
      __syncthreads();
    }
    const int carry = carry_s;
    if (i < N) offs[i + 1] = lds[t] + carry;
    __syncthreads();
    if (t == 1023) carry_s = carry + lds[1023];
    __syncthreads();
  }
}

__global__ void k_fill(const int* __restrict__ src_g, const int* __restrict__ dst_g,
                       const int* __restrict__ offs, int* cursor, int* __restrict__ csr_src, int E)
{
  int e = blockIdx.x * blockDim.x + threadIdx.x;
  if (e >= E) return;
  int d = dst_g[e];
  int p = atomicAdd(&cursor[d], 1);
  csr_src[offs[d] + p] = src_g[e];
}

// ---------- fp32 -> bf16 cast (4 elems/thread) ----------
__global__ void k_cast(const float* __restrict__ in, unsigned short* __restrict__ out, int n4)
{
  int i = blockIdx.x * blockDim.x + threadIdx.x;
  if (i >= n4) return;
  float4 v = ((const float4*)in)[i];
  ushort4 u; u.x = f2bf(v.x); u.y = f2bf(v.y); u.z = f2bf(v.z); u.w = f2bf(v.w);
  ((ushort4*)out)[i] = u;
}

// ---------- weight transpose+cast: Wt[n][k] = bf16(W[k][n]) ----------
__global__ void k_wtrans(const float* __restrict__ W, unsigned short* __restrict__ Wt, int K, int Nc)
{
  int idx = blockIdx.x * blockDim.x + threadIdx.x;
  if (idx >= K * Nc) return;
  int k = idx / Nc, n = idx % Nc;
  Wt[(size_t)n * K + k] = f2bf(W[idx]);
}

// ---------- bf16 MFMA GEMM: C[M,Nc] = A[M,K] @ Wt[Nc,K]^T (+bias, opt relu) ----------
// Tile 128x64, BK=64, 4 waves (2x2), swizzled LDS staged via global_load_lds.
__global__ __launch_bounds__(256) void k_mgemm(
    const unsigned short* __restrict__ A, const unsigned short* __restrict__ Wt,
    const float* __restrict__ bias, float* __restrict__ outf, unsigned short* __restrict__ outb,
    int M, int K, int Nc, int relu)
{
  __shared__ char smem[24576];     // A: 16 KB [128 rows][128 B], B: 8 KB [64 rows][128 B]
  char* As = smem;
  char* Bs = smem + 16384;
  const int tid = threadIdx.x;
  const int lane = tid & 63, w = tid >> 6;
  const int wr = w >> 1, wc = w & 1;
  const int bm = blockIdx.x * 128, bn = blockIdx.y * 64;
  const int srow = lane >> 3;                      // 0..7
  const int scol = ((lane & 7) ^ srow) << 3;       // pre-swizzled source col (elems)
  const int xr = (lane & 7) << 4;                  // read-side XOR (bytes)

  f32x4 acc[4][2];
  #pragma unroll
  for (int mi = 0; mi < 4; ++mi)
    #pragma unroll
    for (int nj = 0; nj < 2; ++nj)
      acc[mi][nj] = (f32x4){0.f, 0.f, 0.f, 0.f};

  for (int k0 = 0; k0 < K; k0 += 64) {
    #pragma unroll
    for (int i = 0; i < 4; ++i) {                  // A: 32 rows/wave
      int row = w * 32 + i * 8 + srow;
      int rg = bm + row; rg = rg < M ? rg : M - 1;
      GLOAD16(A + (size_t)rg * K + k0 + scol, As + (w * 4096 + i * 1024));
    }
    #pragma unroll
    for (int i = 0; i < 2; ++i) {                  // B: 16 n-rows/wave
      int nrow = w * 16 + i * 8 + srow;
      GLOAD16(Wt + (size_t)(bn + nrow) * K + k0 + scol, Bs + (w * 2048 + i * 1024));
    }
    __syncthreads();
    #pragma unroll
    for (int ks = 0; ks < 2; ++ks) {
      const int kb = ks * 64 + ((lane >> 4) << 4);
      bf16x8 af[4], bfr[2];
      #pragma unroll
      for (int mi = 0; mi < 4; ++mi) {
        int row_l = wr * 64 + mi * 16 + (lane & 15);
        af[mi] = *(const bf16x8*)(As + row_l * 128 + (kb ^ xr));
      }
      #pragma unroll
      for (int nj = 0; nj < 2; ++nj) {
        int n_l = wc * 32 + nj * 16 + (lane & 15);
        bfr[nj] = *(const bf16x8*)(Bs + n_l * 128 + (kb ^ xr));
      }
      #pragma unroll
      for (int mi = 0; mi < 4; ++mi)
        #pragma unroll
        for (int nj = 0; nj < 2; ++nj)
          acc[mi][nj] = __builtin_amdgcn_mfma_f32_16x16x32_bf16(af[mi], bfr[nj], acc[mi][nj], 0, 0, 0);
    }
    __syncthreads();
  }

  #pragma unroll
  for (int mi = 0; mi < 4; ++mi) {
    #pragma unroll
    for (int j = 0; j < 4; ++j) {
      int r = bm + wr * 64 + mi * 16 + ((lane >> 4) << 2) + j;
      if (r >= M) continue;
      #pragma unroll
      for (int nj = 0; nj < 2; ++nj) {
        int c = bn + wc * 32 + nj * 16 + (lane & 15);
        float v = acc[mi][nj][j];
        if (bias) v += bias[c];
        if (relu) v = fmaxf(v, 0.f);
        if (outf) outf[(size_t)r * Nc + c] = v;
        if (outb) outb[(size_t)r * Nc + c] = f2bf(v);
      }
    }
  }
}

// ---------- GCN aggregate (bf16 h) + epilogue: out = agg*nd + b, opt relu ----------
__global__ __launch_bounds__(256) void k_agg(const unsigned short* __restrict__ h,
    const int* __restrict__ offs, const int* __restrict__ csr,
    const float* __restrict__ ns, const float* __restrict__ nd, const float* __restrict__ bias,
    float* __restrict__ outf, unsigned short* __restrict__ outb, int F, int relu)
{
  const int tpn = F >> 1;                              // threads per node (2 elems each)
  const int node = blockIdx.x * (256 / tpn) + threadIdx.x / tpn;
  const int j = (threadIdx.x & (tpn - 1)) * 2;
  const int s0 = offs[node], s1 = offs[node + 1];
  float a0 = 0.f, a1 = 0.f;
  for (int k = s0; k < s1; ++k) {
    const int s = csr[k];
    const float wt = ns[s];
    const ushort2 hv = *(const ushort2*)(h + (size_t)s * F + j);
    a0 += b2f(hv.x) * wt;
    a1 += b2f(hv.y) * wt;
  }
  const float ndv = nd[node];
  float o0 = a0 * ndv + bias[j];
  float o1 = a1 * ndv + bias[j + 1];
  if (relu) { o0 = fmaxf(o0, 0.f); o1 = fmaxf(o1, 0.f); }
  if (outf) { outf[(size_t)node * F + j] = o0; outf[(size_t)node * F + j + 1] = o1; }
  if (outb) {
    ushort2 ub; ub.x = f2bf(o0); ub.y = f2bf(o1);
    *(ushort2*)(outb + (size_t)node * F + j) = ub;
  }
}

// ---------- row normalize (fp32 in): optional fp32 out, optional bf16 out ----------
__global__ __launch_bounds__(256) void k_normrows(const float* __restrict__ X,
    float* __restrict__ outf, unsigned short* __restrict__ outb, int Nrows)
{
  const int wid = threadIdx.x >> 6, lane = threadIdx.x & 63;
  const int row = blockIdx.x * 4 + wid;
  if (row >= Nrows) return;
  const float4 v = ((const float4*)(X + (size_t)row * 256))[lane];
  float ss = v.x * v.x + v.y * v.y + v.z * v.z + v.w * v.w;
  #pragma unroll
  for (int m = 1; m < 64; m <<= 1) ss += __shfl_xor(ss, m);
  const float inv = 1.f / fmaxf(sqrtf(ss), 1e-12f);
  float4 o; o.x = v.x * inv; o.y = v.y * inv; o.z = v.z * inv; o.w = v.w * inv;
  if (outf) ((float4*)(outf + (size_t)row * 256))[lane] = o;
  if (outb) {
    ushort4 u;
    u.x = f2bf(o.x); u.y = f2bf(o.y); u.z = f2bf(o.z); u.w = f2bf(o.w);
    ((ushort4*)(outb + (size_t)row * 256))[lane] = u;
  }
}

// ---------- edge sim (bf16): sim[e] = <un[src], q[dst]>/tau ; pos_sum[dst] += sim ----------
__global__ __launch_bounds__(256) void k_edge_sim(const unsigned short* __restrict__ un,
    const unsigned short* __restrict__ q, const int* __restrict__ src, const int* __restrict__ dst,
    const float* __restrict__ tau_p, float* __restrict__ sim, float* __restrict__ pos_sum, int E)
{
  const int w = blockIdx.x * 4 + (threadIdx.x >> 6);
  if (w >= E) return;
  const int lane = threadIdx.x & 63;
  const int s = src[w], d = dst[w];
  const ushort4 a = ((const ushort4*)(un + (size_t)s * 256))[lane];
  const ushort4 b = ((const ushort4*)(q + (size_t)d * 256))[lane];
  float dot = b2f(a.x) * b2f(b.x) + b2f(a.y) * b2f(b.y)
            + b2f(a.z) * b2f(b.z) + b2f(a.w) * b2f(b.w);
  #pragma unroll
  for (int m = 1; m < 64; m <<= 1) dot += __shfl_xor(dot, m);
  if (lane == 0) {
    const float sv = dot / tau_p[0];
    sim[w] = sv;
    atomicAdd(&pos_sum[d], sv);
  }
}

// ---------- neg_sim accumulate (j-split, 4 i-tiles/wave) ----------
#define NEG_JSPLIT 16
__global__ __launch_bounds__(256) void k_negsim(const unsigned short* __restrict__ zb,
                                                const unsigned short* __restrict__ sb,
                                                const float* __restrict__ tau_p,
                                                float* __restrict__ negsim, int N)
{
  __shared__ float4 lds4[64 * 33];   // 64 rows x 512B, pitch 528B
  const int tid = threadIdx.x;
  const int lane = tid & 63, wid = tid >> 6;
  const int ntiles = N >> 4;
  const int quad = blockIdx.x * 4 + wid;
  int itv[4]; bool vv[4];
  #pragma unroll
  for (int t = 0; t < 4; ++t) {
    int it = quad * 4 + t;
    vv[t] = it < ntiles;
    itv[t] = vv[t] ? it : (ntiles - 1);
  }
  const float k_exp = 1.0f / tau_p[0];

  bf16x8 afrag[4][8];
  #pragma unroll
  for (int t = 0; t < 4; ++t) {
    const unsigned short* r = zb + (size_t)((itv[t] << 4) + (lane & 15)) * 256 + ((lane >> 4) << 3);
    #pragma unroll
    for (int ks = 0; ks < 8; ++ks)
      afrag[t][ks] = *(const bf16x8*)(r + ks * 32);
  }

  const int total = 2 * N;
  const int chunk = ((total + NEG_JSPLIT * 64 - 1) / (NEG_JSPLIT * 64)) * 64;
  const int jbeg = blockIdx.y * chunk;
  const int jend = min(total, jbeg + chunk);

  float psum[4][4];
  #pragma unroll
  for (int t = 0; t < 4; ++t)
    #pragma unroll
    for (int j = 0; j < 4; ++j) psum[t][j] = 0.f;

  for (int j0 = jbeg; j0 < jend; j0 += 64) {
    const int rows = min(64, jend - j0);           // multiple of 16
    __syncthreads();
    for (int idx = tid; idx < (rows << 5); idx += 256) {
      const int r = idx >> 5, c = idx & 31;
      const int g = j0 + r;
      const unsigned short* srcp = (g < N) ? (zb + (size_t)g * 256)
                                           : (sb + (size_t)(g - N) * 256);
      lds4[r * 33 + c] = ((const float4*)srcp)[c];
    }
    __syncthreads();
    const int nsub = rows >> 4;
    for (int sub = 0; sub < nsub; ++sub) {
      const float4* bb = &lds4[(sub * 16 + (lane & 15)) * 33 + (lane >> 4)];
      f32x4 acc[4];
      #pragma unroll
      for (int t = 0; t < 4; ++t) acc[t] = (f32x4){0.f, 0.f, 0.f, 0.f};
      #pragma unroll
      for (int ks = 0; ks < 8; ++ks) {
        bf16x8 bfrag = *(const bf16x8*)(bb + ks * 4);
        #pragma unroll
        for (int t = 0; t < 4; ++t)
          acc[t] = __builtin_amdgcn_mfma_f32_16x16x32_bf16(afrag[t][ks], bfrag, acc[t], 0, 0, 0);
      }
      #pragma unroll
      for (int t = 0; t < 4; ++t)
        #pragma unroll
        for (int j = 0; j < 4; ++j)
          psum[t][j] += __expf(acc[t][j] * k_exp);
    }
  }
  #pragma unroll
  for (int t = 0; t < 4; ++t)
    #pragma unroll
    for (int j = 0; j < 4; ++j) {
      float x = psum[t][j];
      x += __shfl_xor(x, 1);
      x += __shfl_xor(x, 2);
      x += __shfl_xor(x, 4);
      x += __shfl_xor(x, 8);
      if (vv[t] && (lane & 15) == 0)
        atomicAdd(&negsim[(itv[t] << 4) + ((lane >> 4) << 2) + j], x);
    }
}

// ---------- edge neg: m = log(neg_sim[dst] + exp(sim)); neg_sum[dst] += m ----------
__global__ void k_edge_neg(const float* __restrict__ negsim, const float* __restrict__ sim,
                           const int* __restrict__ dst, float* __restrict__ neg_sum, int E)
{
  const int e = blockIdx.x * blockDim.x + threadIdx.x;
  if (e >= E) return;
  const int d = dst[e];
  const float m = logf(negsim[d] + __expf(sim[e]));
  atomicAdd(&neg_sum[d], m);
}

// ---------- loss = mean_i (-pos_sum + neg_sum)/max(cnt,1) ----------
__global__ __launch_bounds__(1024) void k_loss(const float* __restrict__ pos, const float* __restrict__ neg,
                                               const int* __restrict__ cnt, int N,
                                               float* __restrict__ out, int add)
{
  __shared__ float lds[1024];
  float s = 0.f;
  for (int i = threadIdx.x; i < N; i += 1024) {
    float denom = fmaxf((float)cnt[i], 1.f);
    s += (-pos[i] + neg[i]) / denom;
  }
  lds[threadIdx.x] = s;
  __syncthreads();
  for (int o = 512; o > 0; o >>= 1) {
    if (threadIdx.x < o) lds[threadIdx.x] += lds[threadIdx.x + o];
    __syncthreads();
  }
  if (threadIdx.x == 0) {
    float v = lds[0] / (float)N;
    if (add) out[0] += v; else out[0] = v;
  }
}

extern "C" void kernel_launch(void* const* d_in, const int* in_sizes, int n_in,
                              void* d_out, int out_size, void* d_ws, size_t ws_size,
                              hipStream_t stream)
{
  const float* feat  = (const float*)d_in[0];
  const int* src_g   = (const int*)d_in[1];
  const int* dst_g   = (const int*)d_in[2];
  const int* src_s   = (const int*)d_in[3];
  const int* dst_s   = (const int*)d_in[4];
  const float* tau1  = (const float*)d_in[5];
  const float* tau2  = (const float*)d_in[6];
  const float* W1a   = (const float*)d_in[7];
  const float* b1a   = (const float*)d_in[8];
  const float* W1b   = (const float*)d_in[9];
  const float* b1b   = (const float*)d_in[10];
  const float* W1a_t = (const float*)d_in[11];
  const float* b1a_t = (const float*)d_in[12];
  const float* W1b_t = (const float*)d_in[13];
  const float* b1b_t = (const float*)d_in[14];
  const float* W2    = (const float*)d_in[15];
  const float* b2    = (const float*)d_in[16];
  const float* W2_t  = (const float*)d_in[17];
  const float* b2_t  = (const float*)d_in[18];
  const float* Wp    = (const float*)d_in[19];
  const float* bp    = (const float*)d_in[20];

  const int N = in_sizes[0] / 512;
  const int E = in_sizes[1];

  float* out  = (float*)d_out;
  float* v1   = out;
  float* u1   = out + (size_t)N * 256;
  float* v2   = out + (size_t)2 * N * 256;
  float* u2   = out + (size_t)3 * N * 256;
  float* loss = out + (size_t)4 * N * 256;

  char* ws = (char*)d_ws;
  size_t off = 0;
  auto alloc = [&](size_t bytes) -> char* {
    char* p = ws + off;
    off += (bytes + 255) & ~(size_t)255;
    return p;
  };
  int* zbase   = (int*)alloc((size_t)10 * N * 4);   // zeroed region
  int* deg_og  = zbase;
  int* deg_ig  = zbase + N;
  int* cnt_s   = zbase + 2 * N;
  int* cursor  = zbase + 3 * N;
  float* pos1  = (float*)(zbase + 4 * N);
  float* neg1  = (float*)(zbase + 5 * N);
  float* pos2  = (float*)(zbase + 6 * N);
  float* neg2  = (float*)(zbase + 7 * N);
  float* negs1 = (float*)(zbase + 8 * N);
  float* negs2 = (float*)(zbase + 9 * N);
  int* offs    = (int*)alloc((size_t)(N + 1) * 4);
  int* csr_src = (int*)alloc((size_t)E * 4);
  float* ns    = (float*)alloc((size_t)N * 4);
  float* nd    = (float*)alloc((size_t)N * 4);
  float* sim   = (float*)alloc((size_t)E * 4);
  unsigned short* featb = (unsigned short*)alloc((size_t)N * 512 * 2);
  unsigned short* wt1a  = (unsigned short*)alloc((size_t)512 * 512 * 2);
  unsigned short* wt1at = (unsigned short*)alloc((size_t)512 * 512 * 2);
  unsigned short* wt1b  = (unsigned short*)alloc((size_t)256 * 512 * 2);
  unsigned short* wt1bt = (unsigned short*)alloc((size_t)256 * 512 * 2);
  unsigned short* wt2   = (unsigned short*)alloc((size_t)256 * 512 * 2);
  unsigned short* wt2t  = (unsigned short*)alloc((size_t)256 * 512 * 2);
  unsigned short* wtp   = (unsigned short*)alloc((size_t)256 * 256 * 2);
  char* BUF_A = alloc((size_t)N * 512 * 2);
  char* BUF_B = alloc((size_t)N * 512 * 2);
  char* BUF_C = alloc((size_t)N * 512 * 2);
  char* BUF_D = alloc((size_t)N * 512 * 2);
  if (off > ws_size) return;  // workspace too small -> visible failure

  unsigned short* h1  = (unsigned short*)BUF_A;
  unsigned short* h1t = (unsigned short*)BUF_B;
  unsigned short* a1  = (unsigned short*)BUF_C;
  unsigned short* a1t = (unsigned short*)BUF_D;
  unsigned short* h2  = (unsigned short*)BUF_A;   // h1 dead
  unsigned short* h2t = (unsigned short*)BUF_B;
  float*          q_raw = (float*)BUF_C;          // a1 dead
  unsigned short* v1b = (unsigned short*)BUF_D;   // a1t dead
  unsigned short* v2b = (unsigned short*)BUF_D + (size_t)N * 256;
  unsigned short* zb  = (unsigned short*)BUF_A;   // h2 dead by scores phase
  unsigned short* unb = (unsigned short*)BUF_A + (size_t)N * 256;  // == sb
  unsigned short* qb  = (unsigned short*)BUF_B;   // h2t dead

  const int eb = (E + 255) / 256;
  const int gmx = (N + 127) / 128;
  const int ntiles = N / 16;
  const int nquads = (ntiles + 3) / 4;
  const dim3 neggrid((nquads + 3) / 4, NEG_JSPLIT);

  hipMemsetAsync(zbase, 0, (size_t)10 * N * 4, stream);
  k_count<<<eb, 256, 0, stream>>>(src_g, dst_g, dst_s, deg_og, deg_ig, cnt_s, E);
  k_norms<<<(N + 255) / 256, 256, 0, stream>>>(deg_og, deg_ig, ns, nd, N);
  k_scan<<<1, 1024, 0, stream>>>(deg_ig, offs, N);
  k_fill<<<eb, 256, 0, stream>>>(src_g, dst_g, offs, cursor, csr_src, E);

  // casts / weight transposes
  k_cast<<<(N * 128 + 255) / 256, 256, 0, stream>>>(feat, featb, N * 128);
  k_wtrans<<<(512 * 512 + 255) / 256, 256, 0, stream>>>(W1a,   wt1a,  512, 512);
  k_wtrans<<<(512 * 512 + 255) / 256, 256, 0, stream>>>(W1a_t, wt1at, 512, 512);
  k_wtrans<<<(512 * 256 + 255) / 256, 256, 0, stream>>>(W1b,   wt1b,  512, 256);
  k_wtrans<<<(512 * 256 + 255) / 256, 256, 0, stream>>>(W1b_t, wt1bt, 512, 256);
  k_wtrans<<<(512 * 256 + 255) / 256, 256, 0, stream>>>(W2,    wt2,   512, 256);
  k_wtrans<<<(512 * 256 + 255) / 256, 256, 0, stream>>>(W2_t,  wt2t,  512, 256);
  k_wtrans<<<(256 * 256 + 255) / 256, 256, 0, stream>>>(Wp,    wtp,   256, 256);

  // GCN encoder (online + target)
  k_mgemm<<<dim3(gmx, 8), 256, 0, stream>>>(featb, wt1a,  nullptr, nullptr, h1,  N, 512, 512, 0);
  k_mgemm<<<dim3(gmx, 8), 256, 0, stream>>>(featb, wt1at, nullptr, nullptr, h1t, N, 512, 512, 0);
  k_agg<<<N, 256, 0, stream>>>(h1,  offs, csr_src, ns, nd, b1a,   nullptr, a1,  512, 1);
  k_agg<<<N, 256, 0, stream>>>(h1t, offs, csr_src, ns, nd, b1a_t, nullptr, a1t, 512, 1);
  k_mgemm<<<dim3(gmx, 4), 256, 0, stream>>>(a1,  wt1b,  nullptr, nullptr, h2,  N, 512, 256, 0);
  k_mgemm<<<dim3(gmx, 4), 256, 0, stream>>>(a1t, wt1bt, nullptr, nullptr, h2t, N, 512, 256, 0);
  // linear encoder (after a1/a1t consumed; v2b lands in BUF_D upper half)
  k_mgemm<<<dim3(gmx, 4), 256, 0, stream>>>(featb, wt2,  b2,   v2, v2b,     N, 512, 256, 0);
  k_mgemm<<<dim3(gmx, 4), 256, 0, stream>>>(featb, wt2t, b2_t, u2, nullptr, N, 512, 256, 0);
  // final GCN aggregates
  k_agg<<<N / 2, 256, 0, stream>>>(h2,  offs, csr_src, ns, nd, b1b,   v1, v1b,     256, 0);
  k_agg<<<N / 2, 256, 0, stream>>>(h2t, offs, csr_src, ns, nd, b1b_t, u1, nullptr, 256, 0);

  // ---- scores branch 1 ----
  k_mgemm<<<dim3(gmx, 4), 256, 0, stream>>>(v1b, wtp, bp, q_raw, nullptr, N, 256, 256, 0);
  k_normrows<<<(N + 3) / 4, 256, 0, stream>>>(q_raw, nullptr, qb,  N);
  k_normrows<<<(N + 3) / 4, 256, 0, stream>>>(u1,    nullptr, unb, N);
  k_normrows<<<(N + 3) / 4, 256, 0, stream>>>(v1,    nullptr, zb,  N);
  k_edge_sim<<<(E + 3) / 4, 256, 0, stream>>>(unb, qb, src_s, dst_s, tau1, sim, pos1, E);
  k_negsim<<<neggrid, 256, 0, stream>>>(zb, unb, tau1, negs1, N);
  k_edge_neg<<<eb, 256, 0, stream>>>(negs1, sim, dst_s, neg1, E);
  k_loss<<<1, 1024, 0, stream>>>(pos1, neg1, cnt_s, N, loss, 0);

  // ---- scores branch 2 ----
  k_mgemm<<<dim3(gmx, 4), 256, 0, stream>>>(v2b, wtp, bp, q_raw, nullptr, N, 256, 256, 0);
  k_normrows<<<(N + 3) / 4, 256, 0, stream>>>(q_raw, nullptr, qb,  N);
  k_normrows<<<(N + 3) / 4, 256, 0, stream>>>(u2,    nullptr, unb, N);
  k_normrows<<<(N + 3) / 4, 256, 0, stream>>>(v2,    nullptr, zb,  N);
  k_edge_sim<<<(E + 3) / 4, 256, 0, stream>>>(unb, qb, src_s, dst_s, tau2, sim, pos2, E);
  k_negsim<<<neggrid, 256, 0, stream>>>(zb, unb, tau2, negs2, N);
  k_edge_neg<<<eb, 256, 0, stream>>>(negs2, sim, dst_s, neg2, E);
  k_loss<<<1, 1024, 0, stream>>>(pos2, neg2, cnt_s, N, loss, 1);
}

// Round 4
// 1019.429 us; speedup vs baseline: 3.2985x; 1.1859x over previous
//
#include <hip/hip_runtime.h>

typedef __bf16 bf16x8 __attribute__((ext_vector_type(8)));
typedef float f32x4 __attribute__((ext_vector_type(4)));

#define GLOAD16(gp, lp) __builtin_amdgcn_global_load_lds( \
    (const __attribute__((address_space(1))) void*)(gp), \
    (__attribute__((address_space(3))) void*)(lp), 16, 0, 0)

__device__ __forceinline__ unsigned short f2bf(float f) {
  union { float f; unsigned u; } c; c.f = f;
  unsigned u = c.u;
  u = (u + 0x7fffu + ((u >> 16) & 1u)) >> 16;
  return (unsigned short)u;
}
__device__ __forceinline__ float b2f(unsigned short u) {
  union { unsigned u; float f; } c; c.u = ((unsigned)u) << 16; return c.f;
}

// ---------- graph prep ----------
__global__ void k_count(const int* __restrict__ src_g, const int* __restrict__ dst_g,
                        const int* __restrict__ dst_s,
                        int* deg_og, int* deg_ig, int* cnt_s, int E)
{
  int e = blockIdx.x * blockDim.x + threadIdx.x;
  if (e >= E) return;
  atomicAdd(&deg_og[src_g[e]], 1);
  atomicAdd(&deg_ig[dst_g[e]], 1);
  atomicAdd(&cnt_s[dst_s[e]], 1);
}

__global__ void k_norms(const int* __restrict__ deg_og, const int* __restrict__ deg_ig,
                        float* __restrict__ ns, float* __restrict__ nd, int N)
{
  int i = blockIdx.x * blockDim.x + threadIdx.x;
  if (i >= N) return;
  int a = deg_og[i]; ns[i] = a > 0 ? rsqrtf((float)a) : 0.f;
  int b = deg_ig[i]; nd[i] = b > 0 ? rsqrtf((float)b) : 0.f;
}

__global__ __launch_bounds__(1024) void k_scan(const int* __restrict__ deg, int* __restrict__ offs, int N)
{
  __shared__ int lds[1024];
  __shared__ int carry_s;
  const int t = threadIdx.x;
  if (t == 0) { carry_s = 0; offs[0] = 0; }
  __syncthreads();
  for (int base = 0; base < N; base += 1024) {
    const int i = base + t;
    int v = (i < N) ? deg[i] : 0;
    lds[t] = v;
    __syncthreads();
    for (int o = 1; o < 1024; o <<= 1) {
      int tmp = (t >= o) ? lds[t - o] : 0;
      __syncthreads();
      lds[t] += tmp;
      __syncthreads();
    }
    const int carry = carry_s;
    if (i < N) offs[i + 1] = lds[t] + carry;
    __syncthreads();
    if (t == 1023) carry_s = carry + lds[1023];
    __syncthreads();
  }
}

__global__ void k_fill(const int* __restrict__ src_g, const int* __restrict__ dst_g,
                       const int* __restrict__ offs, int* cursor, int* __restrict__ csr_src, int E)
{
  int e = blockIdx.x * blockDim.x + threadIdx.x;
  if (e >= E) return;
  int d = dst_g[e];
  int p = atomicAdd(&cursor[d], 1);
  csr_src[offs[d] + p] = src_g[e];
}

// ---------- fp32 -> bf16 cast (4 elems/thread) ----------
__global__ void k_cast(const float* __restrict__ in, unsigned short* __restrict__ out, int n4)
{
  int i = blockIdx.x * blockDim.x + threadIdx.x;
  if (i >= n4) return;
  float4 v = ((const float4*)in)[i];
  ushort4 u; u.x = f2bf(v.x); u.y = f2bf(v.y); u.z = f2bf(v.z); u.w = f2bf(v.w);
  ((ushort4*)out)[i] = u;
}

// ---------- weight transpose+cast: Wt[n][k] = bf16(W[k][n]) ----------
__global__ void k_wtrans(const float* __restrict__ W, unsigned short* __restrict__ Wt, int K, int Nc)
{
  int idx = blockIdx.x * blockDim.x + threadIdx.x;
  if (idx >= K * Nc) return;
  int k = idx / Nc, n = idx % Nc;
  Wt[(size_t)n * K + k] = f2bf(W[idx]);
}

// ---------- bf16 MFMA GEMM: C[M,Nc] = A[M,K] @ Wt[Nc,K]^T (+bias, opt relu) ----------
__global__ __launch_bounds__(256) void k_mgemm(
    const unsigned short* __restrict__ A, const unsigned short* __restrict__ Wt,
    const float* __restrict__ bias, float* __restrict__ outf, unsigned short* __restrict__ outb,
    int M, int K, int Nc, int relu)
{
  __shared__ char smem[24576];     // A: 16 KB [128 rows][128 B], B: 8 KB [64 rows][128 B]
  char* As = smem;
  char* Bs = smem + 16384;
  const int tid = threadIdx.x;
  const int lane = tid & 63, w = tid >> 6;
  const int wr = w >> 1, wc = w & 1;
  const int bm = blockIdx.x * 128, bn = blockIdx.y * 64;
  const int srow = lane >> 3;                      // 0..7
  const int scol = ((lane & 7) ^ srow) << 3;       // pre-swizzled source col (elems)
  const int xr = (lane & 7) << 4;                  // read-side XOR (bytes)

  f32x4 acc[4][2];
  #pragma unroll
  for (int mi = 0; mi < 4; ++mi)
    #pragma unroll
    for (int nj = 0; nj < 2; ++nj)
      acc[mi][nj] = (f32x4){0.f, 0.f, 0.f, 0.f};

  for (int k0 = 0; k0 < K; k0 += 64) {
    #pragma unroll
    for (int i = 0; i < 4; ++i) {                  // A: 32 rows/wave
      int row = w * 32 + i * 8 + srow;
      int rg = bm + row; rg = rg < M ? rg : M - 1;
      GLOAD16(A + (size_t)rg * K + k0 + scol, As + (w * 4096 + i * 1024));
    }
    #pragma unroll
    for (int i = 0; i < 2; ++i) {                  // B: 16 n-rows/wave
      int nrow = w * 16 + i * 8 + srow;
      GLOAD16(Wt + (size_t)(bn + nrow) * K + k0 + scol, Bs + (w * 2048 + i * 1024));
    }
    __syncthreads();
    #pragma unroll
    for (int ks = 0; ks < 2; ++ks) {
      const int kb = ks * 64 + ((lane >> 4) << 4);
      bf16x8 af[4], bfr[2];
      #pragma unroll
      for (int mi = 0; mi < 4; ++mi) {
        int row_l = wr * 64 + mi * 16 + (lane & 15);
        af[mi] = *(const bf16x8*)(As + row_l * 128 + (kb ^ xr));
      }
      #pragma unroll
      for (int nj = 0; nj < 2; ++nj) {
        int n_l = wc * 32 + nj * 16 + (lane & 15);
        bfr[nj] = *(const bf16x8*)(Bs + n_l * 128 + (kb ^ xr));
      }
      #pragma unroll
      for (int mi = 0; mi < 4; ++mi)
        #pragma unroll
        for (int nj = 0; nj < 2; ++nj)
          acc[mi][nj] = __builtin_amdgcn_mfma_f32_16x16x32_bf16(af[mi], bfr[nj], acc[mi][nj], 0, 0, 0);
    }
    __syncthreads();
  }

  #pragma unroll
  for (int mi = 0; mi < 4; ++mi) {
    #pragma unroll
    for (int j = 0; j < 4; ++j) {
      int r = bm + wr * 64 + mi * 16 + ((lane >> 4) << 2) + j;
      if (r >= M) continue;
      #pragma unroll
      for (int nj = 0; nj < 2; ++nj) {
        int c = bn + wc * 32 + nj * 16 + (lane & 15);
        float v = acc[mi][nj][j];
        if (bias) v += bias[c];
        if (relu) v = fmaxf(v, 0.f);
        if (outf) outf[(size_t)r * Nc + c] = v;
        if (outb) outb[(size_t)r * Nc + c] = f2bf(v);
      }
    }
  }
}

// ---------- GCN aggregate (bf16 h): out = agg(ns*h)*nd (+bias) (opt relu) ----------
__global__ __launch_bounds__(256) void k_agg(const unsigned short* __restrict__ h,
    const int* __restrict__ offs, const int* __restrict__ csr,
    const float* __restrict__ ns, const float* __restrict__ nd, const float* __restrict__ bias,
    float* __restrict__ outf, unsigned short* __restrict__ outb, int F, int relu)
{
  const int tpn = F >> 1;                              // threads per node (2 elems each)
  const int node = blockIdx.x * (256 / tpn) + threadIdx.x / tpn;
  const int j = (threadIdx.x & (tpn - 1)) * 2;
  const int s0 = offs[node], s1 = offs[node + 1];
  float a0 = 0.f, a1 = 0.f;
  for (int k = s0; k < s1; ++k) {
    const int s = csr[k];
    const float wt = ns[s];
    const ushort2 hv = *(const ushort2*)(h + (size_t)s * F + j);
    a0 += b2f(hv.x) * wt;
    a1 += b2f(hv.y) * wt;
  }
  const float ndv = nd[node];
  float o0 = a0 * ndv;
  float o1 = a1 * ndv;
  if (bias) { o0 += bias[j]; o1 += bias[j + 1]; }
  if (relu) { o0 = fmaxf(o0, 0.f); o1 = fmaxf(o1, 0.f); }
  if (outf) { outf[(size_t)node * F + j] = o0; outf[(size_t)node * F + j + 1] = o1; }
  if (outb) {
    ushort2 ub; ub.x = f2bf(o0); ub.y = f2bf(o1);
    *(ushort2*)(outb + (size_t)node * F + j) = ub;
  }
}

// ---------- row normalize (fp32 in): optional fp32 out, optional bf16 out ----------
__global__ __launch_bounds__(256) void k_normrows(const float* __restrict__ X,
    float* __restrict__ outf, unsigned short* __restrict__ outb, int Nrows)
{
  const int wid = threadIdx.x >> 6, lane = threadIdx.x & 63;
  const int row = blockIdx.x * 4 + wid;
  if (row >= Nrows) return;
  const float4 v = ((const float4*)(X + (size_t)row * 256))[lane];
  float ss = v.x * v.x + v.y * v.y + v.z * v.z + v.w * v.w;
  #pragma unroll
  for (int m = 1; m < 64; m <<= 1) ss += __shfl_xor(ss, m);
  const float inv = 1.f / fmaxf(sqrtf(ss), 1e-12f);
  float4 o; o.x = v.x * inv; o.y = v.y * inv; o.z = v.z * inv; o.w = v.w * inv;
  if (outf) ((float4*)(outf + (size_t)row * 256))[lane] = o;
  if (outb) {
    ushort4 u;
    u.x = f2bf(o.x); u.y = f2bf(o.y); u.z = f2bf(o.z); u.w = f2bf(o.w);
    ((ushort4*)(outb + (size_t)row * 256))[lane] = u;
  }
}

// ---------- fused edge: sim + pos atomic; m = log(negsim[d]+exp(sim)) + neg atomic ----------
__global__ __launch_bounds__(256) void k_edge_simneg(const unsigned short* __restrict__ un,
    const unsigned short* __restrict__ q, const int* __restrict__ src, const int* __restrict__ dst,
    const float* __restrict__ tau_p, const float* __restrict__ negsim,
    float* __restrict__ pos_sum, float* __restrict__ neg_sum, int E)
{
  const int w = blockIdx.x * 4 + (threadIdx.x >> 6);
  if (w >= E) return;
  const int lane = threadIdx.x & 63;
  const int s = src[w], d = dst[w];
  const ushort4 a = ((const ushort4*)(un + (size_t)s * 256))[lane];
  const ushort4 b = ((const ushort4*)(q + (size_t)d * 256))[lane];
  float dot = b2f(a.x) * b2f(b.x) + b2f(a.y) * b2f(b.y)
            + b2f(a.z) * b2f(b.z) + b2f(a.w) * b2f(b.w);
  #pragma unroll
  for (int m = 1; m < 64; m <<= 1) dot += __shfl_xor(dot, m);
  if (lane == 0) {
    const float sv = dot / tau_p[0];
    atomicAdd(&pos_sum[d], sv);
    const float mlog = logf(negsim[d] + __expf(sv));
    atomicAdd(&neg_sum[d], mlog);
  }
}

// ---------- neg_sim accumulate (j-split 32, 4 i-tiles/wave, XOR-swizzled 32KB LDS) ----------
#define NEG_JSPLIT 32
__global__ __launch_bounds__(256) void k_negsim(const unsigned short* __restrict__ zb,
                                                const unsigned short* __restrict__ sb,
                                                const float* __restrict__ tau_p,
                                                float* __restrict__ negsim, int N)
{
  __shared__ float4 lds4[64 * 32];   // 64 rows x 512B, XOR-swizzled: byte ^= (row&7)<<4
  char* smem = (char*)lds4;
  const int tid = threadIdx.x;
  const int lane = tid & 63, wid = tid >> 6;
  const int ntiles = N >> 4;
  const int quad = blockIdx.x * 4 + wid;
  int itv[4]; bool vv[4];
  #pragma unroll
  for (int t = 0; t < 4; ++t) {
    int it = quad * 4 + t;
    vv[t] = it < ntiles;
    itv[t] = vv[t] ? it : (ntiles - 1);
  }
  const float k_exp = 1.0f / tau_p[0];

  bf16x8 afrag[4][8];
  #pragma unroll
  for (int t = 0; t < 4; ++t) {
    const unsigned short* r = zb + (size_t)((itv[t] << 4) + (lane & 15)) * 256 + ((lane >> 4) << 3);
    #pragma unroll
    for (int ks = 0; ks < 8; ++ks)
      afrag[t][ks] = *(const bf16x8*)(r + ks * 32);
  }

  const int total = 2 * N;
  const int chunk = ((total + NEG_JSPLIT * 64 - 1) / (NEG_JSPLIT * 64)) * 64;
  const int jbeg = blockIdx.y * chunk;
  const int jend = min(total, jbeg + chunk);

  float psum[4][4];
  #pragma unroll
  for (int t = 0; t < 4; ++t)
    #pragma unroll
    for (int j = 0; j < 4; ++j) psum[t][j] = 0.f;

  const int rxor = (lane & 7) << 4;            // read-side row-XOR (row&7 == lane&7)

  for (int j0 = jbeg; j0 < jend; j0 += 64) {
    const int rows = min(64, jend - j0);       // multiple of 16
    __syncthreads();
    for (int idx = tid; idx < (rows << 5); idx += 256) {
      const int r = idx >> 5, c = idx & 31;
      const int g = j0 + r;
      const unsigned short* srcp = (g < N) ? (zb + (size_t)g * 256)
                                           : (sb + (size_t)(g - N) * 256);
      *(float4*)(smem + r * 512 + ((c << 4) ^ ((r & 7) << 4))) = ((const float4*)srcp)[c];
    }
    __syncthreads();
    const int nsub = rows >> 4;
    for (int sub = 0; sub < nsub; ++sub) {
      const char* bb = smem + (sub * 16 + (lane & 15)) * 512;
      const int kbase = (lane >> 4) << 4;
      f32x4 acc[4];
      #pragma unroll
      for (int t = 0; t < 4; ++t) acc[t] = (f32x4){0.f, 0.f, 0.f, 0.f};
      #pragma unroll
      for (int ks = 0; ks < 8; ++ks) {
        bf16x8 bfrag = *(const bf16x8*)(bb + ((kbase + ks * 64) ^ rxor));
        #pragma unroll
        for (int t = 0; t < 4; ++t)
          acc[t] = __builtin_amdgcn_mfma_f32_16x16x32_bf16(afrag[t][ks], bfrag, acc[t], 0, 0, 0);
      }
      #pragma unroll
      for (int t = 0; t < 4; ++t)
        #pragma unroll
        for (int j = 0; j < 4; ++j)
          psum[t][j] += __expf(acc[t][j] * k_exp);
    }
  }
  #pragma unroll
  for (int t = 0; t < 4; ++t)
    #pragma unroll
    for (int j = 0; j < 4; ++j) {
      float x = psum[t][j];
      x += __shfl_xor(x, 1);
      x += __shfl_xor(x, 2);
      x += __shfl_xor(x, 4);
      x += __shfl_xor(x, 8);
      if (vv[t] && (lane & 15) == 0)
        atomicAdd(&negsim[(itv[t] << 4) + ((lane >> 4) << 2) + j], x);
    }
}

// ---------- loss = mean_i (-pos_sum + neg_sum)/max(cnt,1) ----------
__global__ __launch_bounds__(1024) void k_loss(const float* __restrict__ pos, const float* __restrict__ neg,
                                               const int* __restrict__ cnt, int N,
                                               float* __restrict__ out, int add)
{
  __shared__ float lds[1024];
  float s = 0.f;
  for (int i = threadIdx.x; i < N; i += 1024) {
    float denom = fmaxf((float)cnt[i], 1.f);
    s += (-pos[i] + neg[i]) / denom;
  }
  lds[threadIdx.x] = s;
  __syncthreads();
  for (int o = 512; o > 0; o >>= 1) {
    if (threadIdx.x < o) lds[threadIdx.x] += lds[threadIdx.x + o];
    __syncthreads();
  }
  if (threadIdx.x == 0) {
    float v = lds[0] / (float)N;
    if (add) out[0] += v; else out[0] = v;
  }
}

extern "C" void kernel_launch(void* const* d_in, const int* in_sizes, int n_in,
                              void* d_out, int out_size, void* d_ws, size_t ws_size,
                              hipStream_t stream)
{
  const float* feat  = (const float*)d_in[0];
  const int* src_g   = (const int*)d_in[1];
  const int* dst_g   = (const int*)d_in[2];
  const int* src_s   = (const int*)d_in[3];
  const int* dst_s   = (const int*)d_in[4];
  const float* tau1  = (const float*)d_in[5];
  const float* tau2  = (const float*)d_in[6];
  const float* W1a   = (const float*)d_in[7];
  const float* b1a   = (const float*)d_in[8];
  const float* W1b   = (const float*)d_in[9];
  const float* b1b   = (const float*)d_in[10];
  const float* W1a_t = (const float*)d_in[11];
  const float* b1a_t = (const float*)d_in[12];
  const float* W1b_t = (const float*)d_in[13];
  const float* b1b_t = (const float*)d_in[14];
  const float* W2    = (const float*)d_in[15];
  const float* b2    = (const float*)d_in[16];
  const float* W2_t  = (const float*)d_in[17];
  const float* b2_t  = (const float*)d_in[18];
  const float* Wp    = (const float*)d_in[19];
  const float* bp    = (const float*)d_in[20];

  const int N = in_sizes[0] / 512;
  const int E = in_sizes[1];

  float* out  = (float*)d_out;
  float* v1   = out;
  float* u1   = out + (size_t)N * 256;
  float* v2   = out + (size_t)2 * N * 256;
  float* u2   = out + (size_t)3 * N * 256;
  float* loss = out + (size_t)4 * N * 256;

  char* ws = (char*)d_ws;
  size_t off = 0;
  auto alloc = [&](size_t bytes) -> char* {
    char* p = ws + off;
    off += (bytes + 255) & ~(size_t)255;
    return p;
  };
  int* zbase   = (int*)alloc((size_t)10 * N * 4);   // zeroed region
  int* deg_og  = zbase;
  int* deg_ig  = zbase + N;
  int* cnt_s   = zbase + 2 * N;
  int* cursor  = zbase + 3 * N;
  float* pos1  = (float*)(zbase + 4 * N);
  float* neg1  = (float*)(zbase + 5 * N);
  float* pos2  = (float*)(zbase + 6 * N);
  float* neg2  = (float*)(zbase + 7 * N);
  float* negs1 = (float*)(zbase + 8 * N);
  float* negs2 = (float*)(zbase + 9 * N);
  int* offs    = (int*)alloc((size_t)(N + 1) * 4);
  int* csr_src = (int*)alloc((size_t)E * 4);
  float* ns    = (float*)alloc((size_t)N * 4);
  float* nd    = (float*)alloc((size_t)N * 4);
  unsigned short* featb = (unsigned short*)alloc((size_t)N * 512 * 2);
  unsigned short* wt1a  = (unsigned short*)alloc((size_t)512 * 512 * 2);
  unsigned short* wt1at = (unsigned short*)alloc((size_t)512 * 512 * 2);
  unsigned short* wt1b  = (unsigned short*)alloc((size_t)256 * 512 * 2);
  unsigned short* wt1bt = (unsigned short*)alloc((size_t)256 * 512 * 2);
  unsigned short* wt2   = (unsigned short*)alloc((size_t)256 * 512 * 2);
  unsigned short* wt2t  = (unsigned short*)alloc((size_t)256 * 512 * 2);
  unsigned short* wtp   = (unsigned short*)alloc((size_t)256 * 256 * 2);
  char* BUF_A = alloc((size_t)N * 512 * 2);
  char* BUF_B = alloc((size_t)N * 512 * 2);
  char* BUF_C = alloc((size_t)N * 512 * 2);
  char* BUF_D = alloc((size_t)N * 512 * 2);
  char* BUF_E = alloc((size_t)N * 512 * 2);
  if (off > ws_size) return;  // workspace too small -> visible failure

  unsigned short* Xaggb = (unsigned short*)BUF_A;            // shared D^-.5 A D^-.5 X, bf16
  unsigned short* h1  = (unsigned short*)BUF_B;              // relu(Xagg@W1a+b1a)
  unsigned short* h1t = (unsigned short*)BUF_C;
  unsigned short* g2  = (unsigned short*)BUF_D;              // h1@W1b   [N*256]
  unsigned short* g2t = (unsigned short*)BUF_D + (size_t)N * 256;
  unsigned short* v1b = (unsigned short*)BUF_E;              // bf16 copies for q GEMM
  unsigned short* v2b = (unsigned short*)BUF_E + (size_t)N * 256;
  float*          q_raw = (float*)BUF_A;                     // Xagg dead by scores phase
  unsigned short* qb  = (unsigned short*)BUF_B;              // h1 dead
  unsigned short* unb = (unsigned short*)BUF_B + (size_t)N * 256;
  unsigned short* zb  = (unsigned short*)BUF_C;              // h1t dead

  const int eb = (E + 255) / 256;
  const int gmx = (N + 127) / 128;
  const int ntiles = N / 16;
  const int nquads = (ntiles + 3) / 4;
  const dim3 neggrid((nquads + 3) / 4, NEG_JSPLIT);

  hipMemsetAsync(zbase, 0, (size_t)10 * N * 4, stream);
  k_count<<<eb, 256, 0, stream>>>(src_g, dst_g, dst_s, deg_og, deg_ig, cnt_s, E);
  k_norms<<<(N + 255) / 256, 256, 0, stream>>>(deg_og, deg_ig, ns, nd, N);
  k_scan<<<1, 1024, 0, stream>>>(deg_ig, offs, N);
  k_fill<<<eb, 256, 0, stream>>>(src_g, dst_g, offs, cursor, csr_src, E);

  // casts / weight transposes
  k_cast<<<(N * 128 + 255) / 256, 256, 0, stream>>>(feat, featb, N * 128);
  k_wtrans<<<(512 * 512 + 255) / 256, 256, 0, stream>>>(W1a,   wt1a,  512, 512);
  k_wtrans<<<(512 * 512 + 255) / 256, 256, 0, stream>>>(W1a_t, wt1at, 512, 512);
  k_wtrans<<<(512 * 256 + 255) / 256, 256, 0, stream>>>(W1b,   wt1b,  512, 256);
  k_wtrans<<<(512 * 256 + 255) / 256, 256, 0, stream>>>(W1b_t, wt1bt, 512, 256);
  k_wtrans<<<(512 * 256 + 255) / 256, 256, 0, stream>>>(W2,    wt2,   512, 256);
  k_wtrans<<<(512 * 256 + 255) / 256, 256, 0, stream>>>(W2_t,  wt2t,  512, 256);
  k_wtrans<<<(256 * 256 + 255) / 256, 256, 0, stream>>>(Wp,    wtp,   256, 256);

  // Shared layer-1 aggregate (linearity: agg(X@W) == agg(X)@W), then GEMM+bias+relu
  k_agg<<<N, 256, 0, stream>>>(featb, offs, csr_src, ns, nd, nullptr, nullptr, Xaggb, 512, 0);
  k_mgemm<<<dim3(gmx, 8), 256, 0, stream>>>(Xaggb, wt1a,  b1a,   nullptr, h1,  N, 512, 512, 1);
  k_mgemm<<<dim3(gmx, 8), 256, 0, stream>>>(Xaggb, wt1at, b1a_t, nullptr, h1t, N, 512, 512, 1);
  // layer 2: GEMM then aggregate (+bias)
  k_mgemm<<<dim3(gmx, 4), 256, 0, stream>>>(h1,  wt1b,  nullptr, nullptr, g2,  N, 512, 256, 0);
  k_mgemm<<<dim3(gmx, 4), 256, 0, stream>>>(h1t, wt1bt, nullptr, nullptr, g2t, N, 512, 256, 0);
  k_agg<<<N / 2, 256, 0, stream>>>(g2,  offs, csr_src, ns, nd, b1b,   v1, v1b,     256, 0);
  k_agg<<<N / 2, 256, 0, stream>>>(g2t, offs, csr_src, ns, nd, b1b_t, u1, nullptr, 256, 0);
  // linear encoder
  k_mgemm<<<dim3(gmx, 4), 256, 0, stream>>>(featb, wt2,  b2,   v2, v2b,     N, 512, 256, 0);
  k_mgemm<<<dim3(gmx, 4), 256, 0, stream>>>(featb, wt2t, b2_t, u2, nullptr, N, 512, 256, 0);

  // ---- scores branch 1 ----
  k_mgemm<<<dim3(gmx, 4), 256, 0, stream>>>(v1b, wtp, bp, q_raw, nullptr, N, 256, 256, 0);
  k_normrows<<<(N + 3) / 4, 256, 0, stream>>>(q_raw, nullptr, qb,  N);
  k_normrows<<<(N + 3) / 4, 256, 0, stream>>>(u1,    nullptr, unb, N);
  k_normrows<<<(N + 3) / 4, 256, 0, stream>>>(v1,    nullptr, zb,  N);
  k_negsim<<<neggrid, 256, 0, stream>>>(zb, unb, tau1, negs1, N);
  k_edge_simneg<<<(E + 3) / 4, 256, 0, stream>>>(unb, qb, src_s, dst_s, tau1, negs1, pos1, neg1, E);
  k_loss<<<1, 1024, 0, stream>>>(pos1, neg1, cnt_s, N, loss, 0);

  // ---- scores branch 2 ----
  k_mgemm<<<dim3(gmx, 4), 256, 0, stream>>>(v2b, wtp, bp, q_raw, nullptr, N, 256, 256, 0);
  k_normrows<<<(N + 3) / 4, 256, 0, stream>>>(q_raw, nullptr, qb,  N);
  k_normrows<<<(N + 3) / 4, 256, 0, stream>>>(u2,    nullptr, unb, N);
  k_normrows<<<(N + 3) / 4, 256, 0, stream>>>(v2,    nullptr, zb,  N);
  k_negsim<<<neggrid, 256, 0, stream>>>(zb, unb, tau2, negs2, N);
  k_edge_simneg<<<(E + 3) / 4, 256, 0, stream>>>(unb, qb, src_s, dst_s, tau2, negs2, pos2, neg2, E);
  k_loss<<<1, 1024, 0, stream>>>(pos2, neg2, cnt_s, N, loss, 1);
}

// Round 5
// 820.504 us; speedup vs baseline: 4.0982x; 1.2424x over previous
//
#include <hip/hip_runtime.h>

typedef __bf16 bf16x8 __attribute__((ext_vector_type(8)));
typedef float f32x4 __attribute__((ext_vector_type(4)));

#define GLOAD16(gp, lp) __builtin_amdgcn_global_load_lds( \
    (const __attribute__((address_space(1))) void*)(gp), \
    (__attribute__((address_space(3))) void*)(lp), 16, 0, 0)

__device__ __forceinline__ unsigned short f2bf(float f) {
  union { float f; unsigned u; } c; c.f = f;
  unsigned u = c.u;
  u = (u + 0x7fffu + ((u >> 16) & 1u)) >> 16;
  return (unsigned short)u;
}
__device__ __forceinline__ float b2f(unsigned short u) {
  union { unsigned u; float f; } c; c.u = ((unsigned)u) << 16; return c.f;
}

// ---------- graph prep ----------
__global__ void k_count(const int* __restrict__ src_g, const int* __restrict__ dst_g,
                        const int* __restrict__ dst_s,
                        int* deg_og, int* deg_ig, int* cnt_s, int E)
{
  int e = blockIdx.x * blockDim.x + threadIdx.x;
  if (e >= E) return;
  atomicAdd(&deg_og[src_g[e]], 1);
  atomicAdd(&deg_ig[dst_g[e]], 1);
  atomicAdd(&cnt_s[dst_s[e]], 1);
}

__global__ void k_norms(const int* __restrict__ deg_og, const int* __restrict__ deg_ig,
                        float* __restrict__ ns, float* __restrict__ nd, int N)
{
  int i = blockIdx.x * blockDim.x + threadIdx.x;
  if (i >= N) return;
  int a = deg_og[i]; ns[i] = a > 0 ? rsqrtf((float)a) : 0.f;
  int b = deg_ig[i]; nd[i] = b > 0 ? rsqrtf((float)b) : 0.f;
}

__global__ __launch_bounds__(1024) void k_scan(const int* __restrict__ deg, int* __restrict__ offs, int N)
{
  __shared__ int lds[1024];
  __shared__ int carry_s;
  const int t = threadIdx.x;
  if (t == 0) { carry_s = 0; offs[0] = 0; }
  __syncthreads();
  for (int base = 0; base < N; base += 1024) {
    const int i = base + t;
    int v = (i < N) ? deg[i] : 0;
    lds[t] = v;
    __syncthreads();
    for (int o = 1; o < 1024; o <<= 1) {
      int tmp = (t >= o) ? lds[t - o] : 0;
      __syncthreads();
      lds[t] += tmp;
      __syncthreads();
    }
    const int carry = carry_s;
    if (i < N) offs[i + 1] = lds[t] + carry;
    __syncthreads();
    if (t == 1023) carry_s = carry + lds[1023];
    __syncthreads();
  }
}

__global__ void k_fill(const int* __restrict__ src_g, const int* __restrict__ dst_g,
                       const int* __restrict__ offs, int* cursor, int* __restrict__ csr_src, int E)
{
  int e = blockIdx.x * blockDim.x + threadIdx.x;
  if (e >= E) return;
  int d = dst_g[e];
  int p = atomicAdd(&cursor[d], 1);
  csr_src[offs[d] + p] = src_g[e];
}

// ---------- one-shot prep: feat cast + all weight transposes/concats + bias concats ----------
struct PrepArgs {
  const float *feat, *W1a, *W1at, *W1b, *W1bt, *W2, *W2t, *Wp;
  const float *b1a, *b1at, *b1b, *b1bt, *b2, *b2t;
  unsigned short *featb, *wcatL1, *wcat2, *wcatLin, *wtp;
  float *bcatL1, *bcatGcn, *bcatLin;
  int NF;
};
__global__ void k_prep(PrepArgs p)
{
  int i = blockIdx.x * blockDim.x + threadIdx.x;
  if (i < p.NF) { p.featb[i] = f2bf(p.feat[i]); return; }
  i -= p.NF;
  if (i < 1024 * 512) {
    int n = i >> 9, k = i & 511;
    p.wcatL1[i] = f2bf(n < 512 ? p.W1a[k * 512 + n] : p.W1at[k * 512 + n - 512]);
    return;
  }
  i -= 1024 * 512;
  if (i < 512 * 512) {
    int n = i >> 9, k = i & 511;
    p.wcat2[i] = f2bf(n < 256 ? p.W1b[k * 256 + n] : p.W1bt[k * 256 + n - 256]);
    return;
  }
  i -= 512 * 512;
  if (i < 512 * 512) {
    int n = i >> 9, k = i & 511;
    p.wcatLin[i] = f2bf(n < 256 ? p.W2[k * 256 + n] : p.W2t[k * 256 + n - 256]);
    return;
  }
  i -= 512 * 512;
  if (i < 256 * 256) {
    int n = i >> 8, k = i & 255;
    p.wtp[i] = f2bf(p.Wp[k * 256 + n]);
    return;
  }
  i -= 256 * 256;
  if (i < 1024) { p.bcatL1[i] = i < 512 ? p.b1a[i] : p.b1at[i - 512]; return; }
  i -= 1024;
  if (i < 512) { p.bcatGcn[i] = i < 256 ? p.b1b[i] : p.b1bt[i - 256]; return; }
  i -= 512;
  if (i < 512) { p.bcatLin[i] = i < 256 ? p.b2[i] : p.b2t[i - 256]; return; }
}

// ---------- bf16 MFMA GEMM: C[M,Nc] = A[M,K](lda) @ Wt[Nc,K]^T (+bias, opt relu) ----------
// asel>0: output cols >= asel read A columns [K, 2K) (block-diagonal dual GEMM).
// splitM>0: output col c<256 -> outf row r; c>=256 -> outf row r+splitM (col c&255, stride 256);
//           outb written only for c<256 (stride 256).
__global__ __launch_bounds__(256) void k_mgemm(
    const unsigned short* __restrict__ A, int lda,
    const unsigned short* __restrict__ Wt,
    const float* __restrict__ bias, float* __restrict__ outf, unsigned short* __restrict__ outb,
    int M, int K, int Nc, int relu, int asel, int splitM)
{
  __shared__ char smem[24576];     // A: 16 KB [128 rows][128 B], B: 8 KB [64 rows][128 B]
  char* As = smem;
  char* Bs = smem + 16384;
  const int tid = threadIdx.x;
  const int lane = tid & 63, w = tid >> 6;
  const int wr = w >> 1, wc = w & 1;
  const int bm = blockIdx.x * 128, bn = blockIdx.y * 64;
  const int aoff = (asel > 0 && bn >= asel) ? K : 0;
  const int srow = lane >> 3;                      // 0..7
  const int scol = ((lane & 7) ^ srow) << 3;       // pre-swizzled source col (elems)
  const int xr = (lane & 7) << 4;                  // read-side XOR (bytes)

  f32x4 acc[4][2];
  #pragma unroll
  for (int mi = 0; mi < 4; ++mi)
    #pragma unroll
    for (int nj = 0; nj < 2; ++nj)
      acc[mi][nj] = (f32x4){0.f, 0.f, 0.f, 0.f};

  for (int k0 = 0; k0 < K; k0 += 64) {
    #pragma unroll
    for (int i = 0; i < 4; ++i) {                  // A: 32 rows/wave
      int row = w * 32 + i * 8 + srow;
      int rg = bm + row; rg = rg < M ? rg : M - 1;
      GLOAD16(A + (size_t)rg * lda + aoff + k0 + scol, As + (w * 4096 + i * 1024));
    }
    #pragma unroll
    for (int i = 0; i < 2; ++i) {                  // B: 16 n-rows/wave
      int nrow = w * 16 + i * 8 + srow;
      GLOAD16(Wt + (size_t)(bn + nrow) * K + k0 + scol, Bs + (w * 2048 + i * 1024));
    }
    __syncthreads();
    #pragma unroll
    for (int ks = 0; ks < 2; ++ks) {
      const int kb = ks * 64 + ((lane >> 4) << 4);
      bf16x8 af[4], bfr[2];
      #pragma unroll
      for (int mi = 0; mi < 4; ++mi) {
        int row_l = wr * 64 + mi * 16 + (lane & 15);
        af[mi] = *(const bf16x8*)(As + row_l * 128 + (kb ^ xr));
      }
      #pragma unroll
      for (int nj = 0; nj < 2; ++nj) {
        int n_l = wc * 32 + nj * 16 + (lane & 15);
        bfr[nj] = *(const bf16x8*)(Bs + n_l * 128 + (kb ^ xr));
      }
      __builtin_amdgcn_s_setprio(1);
      #pragma unroll
      for (int mi = 0; mi < 4; ++mi)
        #pragma unroll
        for (int nj = 0; nj < 2; ++nj)
          acc[mi][nj] = __builtin_amdgcn_mfma_f32_16x16x32_bf16(af[mi], bfr[nj], acc[mi][nj], 0, 0, 0);
      __builtin_amdgcn_s_setprio(0);
    }
    __syncthreads();
  }

  #pragma unroll
  for (int mi = 0; mi < 4; ++mi) {
    #pragma unroll
    for (int j = 0; j < 4; ++j) {
      int r = bm + wr * 64 + mi * 16 + ((lane >> 4) << 2) + j;
      if (r >= M) continue;
      #pragma unroll
      for (int nj = 0; nj < 2; ++nj) {
        int c = bn + wc * 32 + nj * 16 + (lane & 15);
        float v = acc[mi][nj][j];
        if (bias) v += bias[c];
        if (relu) v = fmaxf(v, 0.f);
        if (splitM > 0) {
          int rr = r + (c >= 256 ? splitM : 0);
          if (outf) outf[(size_t)rr * 256 + (c & 255)] = v;
          if (outb && c < 256) outb[(size_t)r * 256 + c] = f2bf(v);
        } else {
          if (outf) outf[(size_t)r * Nc + c] = v;
          if (outb) outb[(size_t)r * Nc + c] = f2bf(v);
        }
      }
    }
  }
}

// ---------- GCN aggregate (bf16 h): out = agg(ns*h)*nd (+bias) (opt relu) ----------
// splitM>0 (F==512): col j<256 -> outf row node; j>=256 -> row node+splitM (col j&255, stride 256);
//                    outb only for j<256.
__global__ __launch_bounds__(256) void k_agg(const unsigned short* __restrict__ h,
    const int* __restrict__ offs, const int* __restrict__ csr,
    const float* __restrict__ ns, const float* __restrict__ nd, const float* __restrict__ bias,
    float* __restrict__ outf, unsigned short* __restrict__ outb, int F, int relu, int splitM)
{
  const int tpn = F >> 1;                              // threads per node (2 elems each)
  const int node = blockIdx.x * (256 / tpn) + threadIdx.x / tpn;
  const int j = (threadIdx.x & (tpn - 1)) * 2;
  const int s0 = offs[node], s1 = offs[node + 1];
  float a0 = 0.f, a1 = 0.f;
  for (int k = s0; k < s1; ++k) {
    const int s = csr[k];
    const float wt = ns[s];
    const ushort2 hv = *(const ushort2*)(h + (size_t)s * F + j);
    a0 += b2f(hv.x) * wt;
    a1 += b2f(hv.y) * wt;
  }
  const float ndv = nd[node];
  float o0 = a0 * ndv;
  float o1 = a1 * ndv;
  if (bias) { o0 += bias[j]; o1 += bias[j + 1]; }
  if (relu) { o0 = fmaxf(o0, 0.f); o1 = fmaxf(o1, 0.f); }
  if (splitM > 0) {
    const int rr = node + (j >= 256 ? splitM : 0);
    const int cc = j & 255;
    if (outf) { outf[(size_t)rr * 256 + cc] = o0; outf[(size_t)rr * 256 + cc + 1] = o1; }
    if (outb && j < 256) {
      ushort2 ub; ub.x = f2bf(o0); ub.y = f2bf(o1);
      *(ushort2*)(outb + (size_t)node * 256 + j) = ub;
    }
  } else {
    if (outf) { outf[(size_t)node * F + j] = o0; outf[(size_t)node * F + j + 1] = o1; }
    if (outb) {
      ushort2 ub; ub.x = f2bf(o0); ub.y = f2bf(o1);
      *(ushort2*)(outb + (size_t)node * F + j) = ub;
    }
  }
}

// ---------- row normalize (fp32 in) -> bf16 out ----------
__global__ __launch_bounds__(256) void k_normrows(const float* __restrict__ X,
    unsigned short* __restrict__ outb, int Nrows)
{
  const int wid = threadIdx.x >> 6, lane = threadIdx.x & 63;
  const int row = blockIdx.x * 4 + wid;
  if (row >= Nrows) return;
  const float4 v = ((const float4*)(X + (size_t)row * 256))[lane];
  float ss = v.x * v.x + v.y * v.y + v.z * v.z + v.w * v.w;
  #pragma unroll
  for (int m = 1; m < 64; m <<= 1) ss += __shfl_xor(ss, m);
  const float inv = 1.f / fmaxf(sqrtf(ss), 1e-12f);
  ushort4 u;
  u.x = f2bf(v.x * inv); u.y = f2bf(v.y * inv);
  u.z = f2bf(v.z * inv); u.w = f2bf(v.w * inv);
  ((ushort4*)(outb + (size_t)row * 256))[lane] = u;
}

// ---------- fused edge (both branches via blockIdx.y) ----------
__global__ __launch_bounds__(256) void k_edge(
    const unsigned short* __restrict__ zun1, const unsigned short* __restrict__ zun2,
    const unsigned short* __restrict__ qb,
    const int* __restrict__ src, const int* __restrict__ dst,
    const float* __restrict__ tau1p, const float* __restrict__ tau2p,
    const float* __restrict__ negs1, const float* __restrict__ negs2,
    float* __restrict__ pos1, float* __restrict__ neg1,
    float* __restrict__ pos2, float* __restrict__ neg2, int N, int E)
{
  const int w = blockIdx.x * 4 + (threadIdx.x >> 6);
  if (w >= E) return;
  const int z = blockIdx.y;
  const unsigned short* un = (z ? zun2 : zun1) + (size_t)N * 256;
  const unsigned short* q = qb + (size_t)z * N * 256;
  const float* negsim = z ? negs2 : negs1;
  float* pos = z ? pos2 : pos1;
  float* neg = z ? neg2 : neg1;
  const int lane = threadIdx.x & 63;
  const int s = src[w], d = dst[w];
  const ushort4 a = ((const ushort4*)(un + (size_t)s * 256))[lane];
  const ushort4 b = ((const ushort4*)(q + (size_t)d * 256))[lane];
  float dot = b2f(a.x) * b2f(b.x) + b2f(a.y) * b2f(b.y)
            + b2f(a.z) * b2f(b.z) + b2f(a.w) * b2f(b.w);
  #pragma unroll
  for (int m = 1; m < 64; m <<= 1) dot += __shfl_xor(dot, m);
  if (lane == 0) {
    const float sv = dot / (z ? tau2p[0] : tau1p[0]);
    atomicAdd(&pos[d], sv);
    const float mlog = logf(negsim[d] + __expf(sv));
    atomicAdd(&neg[d], mlog);
  }
}

// ---------- neg_sim: both branches (blockIdx.z), j-split, 4 i-tiles/wave,
//            double-buffered LDS staged by global_load_lds (linear dest, pre-swizzled source) ----------
#define NEG_JSPLIT 32
__global__ __launch_bounds__(256) void k_negsim(
    const unsigned short* __restrict__ zun1, const unsigned short* __restrict__ zun2,
    const float* __restrict__ tau1p, const float* __restrict__ tau2p,
    float* __restrict__ negs1, float* __restrict__ negs2, int N)
{
  __shared__ char smem[65536];     // 2 x 32KB j-tiles (64 rows x 512B, XOR-swizzled layout)
  const int tid = threadIdx.x;
  const int lane = tid & 63, wid = tid >> 6;
  const int z = blockIdx.z;
  const unsigned short* zun = z ? zun2 : zun1;
  float* negsim = z ? negs2 : negs1;
  const float k_exp = 1.0f / (z ? tau2p[0] : tau1p[0]);
  const int ntiles = N >> 4;
  const int quad = blockIdx.x * 4 + wid;
  int itv[4]; bool vv[4];
  #pragma unroll
  for (int t = 0; t < 4; ++t) {
    int it = quad * 4 + t;
    vv[t] = it < ntiles;
    itv[t] = vv[t] ? it : (ntiles - 1);
  }

  bf16x8 afrag[4][8];
  #pragma unroll
  for (int t = 0; t < 4; ++t) {
    const unsigned short* r = zun + (size_t)((itv[t] << 4) + (lane & 15)) * 256 + ((lane >> 4) << 3);
    #pragma unroll
    for (int ks = 0; ks < 8; ++ks)
      afrag[t][ks] = *(const bf16x8*)(r + ks * 32);
  }

  const int total = 2 * N;
  const int chunk = ((total + NEG_JSPLIT * 64 - 1) / (NEG_JSPLIT * 64)) * 64;
  const int jbeg = blockIdx.y * chunk;
  const int jend = min(total, jbeg + chunk);
  if (jbeg >= jend) return;

  float psum[4][4];
  #pragma unroll
  for (int t = 0; t < 4; ++t)
    #pragma unroll
    for (int j = 0; j < 4; ++j) psum[t][j] = 0.f;

  // stage: LDS[r][c] = G[j0+r][c ^ (r&7)]  (16B units); dest linear per lane (rule #21)
  auto stage = [&](int buf, int j0) {
    #pragma unroll
    for (int i = 0; i < 8; ++i) {
      int idx = tid + 256 * i;
      int r = idx >> 5, c = idx & 31;
      int g = j0 + r; g = g < total ? g : total - 1;
      int cp = c ^ (r & 7);
      GLOAD16(zun + (size_t)g * 256 + cp * 8, smem + buf * 32768 + r * 512 + c * 16);
    }
  };

  const int rxor = (lane & 7) << 4;
  const int kcol = (lane >> 4) << 4;
  int cur = 0;
  stage(0, jbeg);
  __syncthreads();                         // drains vmcnt + barrier
  for (int j0 = jbeg; j0 < jend; j0 += 64) {
    if (j0 + 64 < jend) stage(cur ^ 1, j0 + 64);   // async, overlaps compute below
    const int rows = min(64, jend - j0);   // multiple of 16
    const int nsub = rows >> 4;
    const char* base = smem + cur * 32768;
    for (int sub = 0; sub < nsub; ++sub) {
      const char* bb = base + (sub * 16 + (lane & 15)) * 512;
      f32x4 acc[4];
      #pragma unroll
      for (int t = 0; t < 4; ++t) acc[t] = (f32x4){0.f, 0.f, 0.f, 0.f};
      __builtin_amdgcn_s_setprio(1);
      #pragma unroll
      for (int ks = 0; ks < 8; ++ks) {
        bf16x8 bfrag = *(const bf16x8*)(bb + ((kcol + ks * 64) ^ rxor));
        #pragma unroll
        for (int t = 0; t < 4; ++t)
          acc[t] = __builtin_amdgcn_mfma_f32_16x16x32_bf16(afrag[t][ks], bfrag, acc[t], 0, 0, 0);
      }
      __builtin_amdgcn_s_setprio(0);
      #pragma unroll
      for (int t = 0; t < 4; ++t)
        #pragma unroll
        for (int j = 0; j < 4; ++j)
          psum[t][j] += __expf(acc[t][j] * k_exp);
    }
    __syncthreads();                       // drains next-tile GLOADs; protects cur buffer
    cur ^= 1;
  }
  #pragma unroll
  for (int t = 0; t < 4; ++t)
    #pragma unroll
    for (int j = 0; j < 4; ++j) {
      float x = psum[t][j];
      x += __shfl_xor(x, 1);
      x += __shfl_xor(x, 2);
      x += __shfl_xor(x, 4);
      x += __shfl_xor(x, 8);
      if (vv[t] && (lane & 15) == 0)
        atomicAdd(&negsim[(itv[t] << 4) + ((lane >> 4) << 2) + j], x);
    }
}

// ---------- loss = mean(-pos1+neg1)/cnt + mean(-pos2+neg2)/cnt ----------
__global__ __launch_bounds__(1024) void k_loss(
    const float* __restrict__ pos1, const float* __restrict__ neg1,
    const float* __restrict__ pos2, const float* __restrict__ neg2,
    const int* __restrict__ cnt, int N, float* __restrict__ out)
{
  __shared__ float lds[1024];
  float s = 0.f;
  for (int i = threadIdx.x; i < N; i += 1024) {
    float denom = fmaxf((float)cnt[i], 1.f);
    s += ((-pos1[i] + neg1[i]) + (-pos2[i] + neg2[i])) / denom;
  }
  lds[threadIdx.x] = s;
  __syncthreads();
  for (int o = 512; o > 0; o >>= 1) {
    if (threadIdx.x < o) lds[threadIdx.x] += lds[threadIdx.x + o];
    __syncthreads();
  }
  if (threadIdx.x == 0) out[0] = lds[0] / (float)N;
}

extern "C" void kernel_launch(void* const* d_in, const int* in_sizes, int n_in,
                              void* d_out, int out_size, void* d_ws, size_t ws_size,
                              hipStream_t stream)
{
  const float* feat  = (const float*)d_in[0];
  const int* src_g   = (const int*)d_in[1];
  const int* dst_g   = (const int*)d_in[2];
  const int* src_s   = (const int*)d_in[3];
  const int* dst_s   = (const int*)d_in[4];
  const float* tau1  = (const float*)d_in[5];
  const float* tau2  = (const float*)d_in[6];
  const float* W1a   = (const float*)d_in[7];
  const float* b1a   = (const float*)d_in[8];
  const float* W1b   = (const float*)d_in[9];
  const float* b1b   = (const float*)d_in[10];
  const float* W1a_t = (const float*)d_in[11];
  const float* b1a_t = (const float*)d_in[12];
  const float* W1b_t = (const float*)d_in[13];
  const float* b1b_t = (const float*)d_in[14];
  const float* W2    = (const float*)d_in[15];
  const float* b2    = (const float*)d_in[16];
  const float* W2_t  = (const float*)d_in[17];
  const float* b2_t  = (const float*)d_in[18];
  const float* Wp    = (const float*)d_in[19];
  const float* bp    = (const float*)d_in[20];

  const int N = in_sizes[0] / 512;
  const int E = in_sizes[1];

  float* out  = (float*)d_out;
  float* v1u1 = out;                               // rows 0..2N-1 (v1 then u1)
  float* v2u2 = out + (size_t)2 * N * 256;         // rows 0..2N-1 (v2 then u2)
  float* loss = out + (size_t)4 * N * 256;

  char* ws = (char*)d_ws;
  size_t off = 0;
  auto alloc = [&](size_t bytes) -> char* {
    char* p = ws + off;
    off += (bytes + 255) & ~(size_t)255;
    return p;
  };
  int* zbase   = (int*)alloc((size_t)10 * N * 4);   // zeroed region
  int* deg_og  = zbase;
  int* deg_ig  = zbase + N;
  int* cnt_s   = zbase + 2 * N;
  int* cursor  = zbase + 3 * N;
  float* pos1  = (float*)(zbase + 4 * N);
  float* neg1  = (float*)(zbase + 5 * N);
  float* pos2  = (float*)(zbase + 6 * N);
  float* neg2  = (float*)(zbase + 7 * N);
  float* negs1 = (float*)(zbase + 8 * N);
  float* negs2 = (float*)(zbase + 9 * N);
  int* offs    = (int*)alloc((size_t)(N + 1) * 4);
  int* csr_src = (int*)alloc((size_t)E * 4);
  float* ns    = (float*)alloc((size_t)N * 4);
  float* nd    = (float*)alloc((size_t)N * 4);
  unsigned short* featb   = (unsigned short*)alloc((size_t)N * 512 * 2);
  unsigned short* wcatL1  = (unsigned short*)alloc((size_t)1024 * 512 * 2);
  unsigned short* wcat2   = (unsigned short*)alloc((size_t)512 * 512 * 2);
  unsigned short* wcatLin = (unsigned short*)alloc((size_t)512 * 512 * 2);
  unsigned short* wtp     = (unsigned short*)alloc((size_t)256 * 256 * 2);
  float* bcatL1  = (float*)alloc(1024 * 4);
  float* bcatGcn = (float*)alloc(512 * 4);
  float* bcatLin = (float*)alloc(512 * 4);
  char* BUF_H = alloc((size_t)N * 2048);  // hcat [N][1024] bf16 -> q_raw [2N][256] f32
  char* BUF_A = alloc((size_t)N * 1024);  // Xaggb -> g2cat -> qb
  char* BUF_B = alloc((size_t)N * 1024);  // zun1 [2N][256] bf16
  char* BUF_C = alloc((size_t)N * 1024);  // zun2
  char* BUF_E = alloc((size_t)N * 1024);  // v1b || v2b
  if (off > ws_size) return;  // workspace too small -> visible failure

  unsigned short* Xaggb = (unsigned short*)BUF_A;
  unsigned short* hcat  = (unsigned short*)BUF_H;
  unsigned short* g2cat = (unsigned short*)BUF_A;            // Xaggb dead after gemmL1
  unsigned short* v1b   = (unsigned short*)BUF_E;
  unsigned short* v2b   = (unsigned short*)BUF_E + (size_t)N * 256;
  float*          q_raw = (float*)BUF_H;                     // hcat dead after gemmL2
  unsigned short* qb    = (unsigned short*)BUF_A;            // g2cat dead after aggdual
  unsigned short* zun1  = (unsigned short*)BUF_B;
  unsigned short* zun2  = (unsigned short*)BUF_C;

  const int eb = (E + 255) / 256;
  const int gmx = (N + 127) / 128;
  const int gqx = (2 * N + 127) / 128;
  const int ntiles = N / 16;
  const int nquads = (ntiles + 3) / 4;
  const dim3 neggrid((nquads + 3) / 4, NEG_JSPLIT, 2);
  const dim3 edgegrid((E + 3) / 4, 2);
  const int nrm2 = (2 * N + 3) / 4;

  hipMemsetAsync(zbase, 0, (size_t)10 * N * 4, stream);
  k_count<<<eb, 256, 0, stream>>>(src_g, dst_g, dst_s, deg_og, deg_ig, cnt_s, E);
  k_norms<<<(N + 255) / 256, 256, 0, stream>>>(deg_og, deg_ig, ns, nd, N);
  k_scan<<<1, 1024, 0, stream>>>(deg_ig, offs, N);
  k_fill<<<eb, 256, 0, stream>>>(src_g, dst_g, offs, cursor, csr_src, E);

  PrepArgs pa;
  pa.feat = feat; pa.W1a = W1a; pa.W1at = W1a_t; pa.W1b = W1b; pa.W1bt = W1b_t;
  pa.W2 = W2; pa.W2t = W2_t; pa.Wp = Wp;
  pa.b1a = b1a; pa.b1at = b1a_t; pa.b1b = b1b; pa.b1bt = b1b_t; pa.b2 = b2; pa.b2t = b2_t;
  pa.featb = featb; pa.wcatL1 = wcatL1; pa.wcat2 = wcat2; pa.wcatLin = wcatLin; pa.wtp = wtp;
  pa.bcatL1 = bcatL1; pa.bcatGcn = bcatGcn; pa.bcatLin = bcatLin;
  pa.NF = N * 512;
  const int ptotal = pa.NF + 1024 * 512 + 512 * 512 + 512 * 512 + 256 * 256 + 1024 + 512 + 512;
  k_prep<<<(ptotal + 255) / 256, 256, 0, stream>>>(pa);

  // Shared layer-1 aggregate (agg(X@W) == agg(X)@W), then concat GEMMs
  k_agg<<<N, 256, 0, stream>>>(featb, offs, csr_src, ns, nd, nullptr, nullptr, Xaggb, 512, 0, 0);
  k_mgemm<<<dim3(gmx, 16), 256, 0, stream>>>(Xaggb, 512, wcatL1, bcatL1, nullptr, hcat,
                                             N, 512, 1024, 1, 0, 0);
  k_mgemm<<<dim3(gmx, 8), 256, 0, stream>>>(hcat, 1024, wcat2, nullptr, nullptr, g2cat,
                                            N, 512, 512, 0, 256, 0);
  k_agg<<<N, 256, 0, stream>>>(g2cat, offs, csr_src, ns, nd, bcatGcn, v1u1, v1b, 512, 0, N);
  k_mgemm<<<dim3(gmx, 8), 256, 0, stream>>>(featb, 512, wcatLin, bcatLin, v2u2, v2b,
                                            N, 512, 512, 0, 0, N);
  // projector for both branches in one GEMM (A = v1b||v2b, 2N rows)
  k_mgemm<<<dim3(gqx, 4), 256, 0, stream>>>((unsigned short*)BUF_E, 256, wtp, bp, q_raw, nullptr,
                                            2 * N, 256, 256, 0, 0, 0);

  // normalizations (each covers 2N rows)
  k_normrows<<<nrm2, 256, 0, stream>>>(v1u1, zun1, 2 * N);
  k_normrows<<<nrm2, 256, 0, stream>>>(v2u2, zun2, 2 * N);
  k_normrows<<<nrm2, 256, 0, stream>>>(q_raw, qb, 2 * N);

  // scores (both branches per dispatch)
  k_negsim<<<neggrid, 256, 0, stream>>>(zun1, zun2, tau1, tau2, negs1, negs2, N);
  k_edge<<<edgegrid, 256, 0, stream>>>(zun1, zun2, qb, src_s, dst_s, tau1, tau2,
                                       negs1, negs2, pos1, neg1, pos2, neg2, N, E);
  k_loss<<<1, 1024, 0, stream>>>(pos1, neg1, pos2, neg2, cnt_s, N, loss);
}